// Round 2
// baseline (379.206 us; speedup 1.0000x reference)
//
#include <hip/hip_runtime.h>

// MaskedSelfAttention: B=4, S=4096, D=1024, H=128. fp32 in/out, bf16 MFMA compute.
// v9: occupancy push. Flash per-wave-iter latency is a ~fixed serial chain
// (v7 vs v8: wall scaled with resident waves); so: 4 blocks/CU (VGPR 124<=128,
// LDS 34KB<=40KB already fit) + chunk C=5 -> 896 uniform blocks, all resident.
// Host tiers C by ws_size (C=5 needs 35.5MiB; C=6 29.9; C=10 = v8's proven
// 21.2MiB). qkv_gemm: 3 blocks/CU (pad 68) + same-XCD grouping of the 3 QKV
// blocks per x-slab (x read 1x from HBM). s_setprio around flash MFMA.

typedef __bf16 bf16x8 __attribute__((ext_vector_type(8)));
typedef __bf16 bf16x4 __attribute__((ext_vector_type(4)));
typedef __bf16 bf16x2 __attribute__((ext_vector_type(2)));
typedef float  f32x4  __attribute__((ext_vector_type(4)));

#define MFMA16(a, b, c) __builtin_amdgcn_mfma_f32_16x16x32_bf16(a, b, c, 0, 0, 0)
#define EXP2F(x) __builtin_amdgcn_exp2f(x)

// ---------------------------------------------------------------- prep_w ----
__global__ __launch_bounds__(256) void prep_w(
    const float* __restrict__ Wq, const float* __restrict__ Wk,
    const float* __restrict__ Wv, __bf16* __restrict__ Wb)
{
    int i = (blockIdx.x * 256 + threadIdx.x) * 4;
    int row = i >> 10;
    const float* W = (row < 128) ? Wq : (row < 256) ? Wk : Wv;
    float4 v = *(const float4*)&W[(size_t)(row & 127) * 1024 + (i & 1023)];
    bf16x4 pk = {(__bf16)v.x, (__bf16)v.y, (__bf16)v.z, (__bf16)v.w};
    *(bf16x4*)&Wb[i] = pk;
}

// -------------------------------------------------------------- qkv_gemm ----
// v9: 3 blocks/CU (LDS pad 72->68 => 52.2KB, launch_bounds(256,3)); the 3 QKV
// blocks of one x-slab are mapped to the SAME XCD (xcd = bx&7 assumed
// round-robin) so the 256KB slab is fetched from HBM once and L2-served twice.
__global__ __launch_bounds__(256, 3) void qkv_gemm(
    const float* __restrict__ x, const __bf16* __restrict__ Wb,
    const float* __restrict__ bq, const float* __restrict__ bk,
    const float* __restrict__ bv,
    __bf16* __restrict__ Qb, __bf16* __restrict__ Kb, __bf16* __restrict__ Vt)
{
    __shared__ __bf16 As[2][64][68];
    __shared__ __bf16 Bs[2][128][68];

    const int tid   = threadIdx.x;
    const int bx    = blockIdx.x;
    const int xcd   = bx & 7, w8 = bx >> 3;   // 96 blocks per xcd
    const int slab  = xcd * 32 + w8 / 3;      // 0..255
    const int which = w8 % 3;                 // 0=Q 1=K 2=V
    const int m0    = slab * 64;
    const int n0    = which * 128;
    const int lane = tid & 63, wid = tid >> 6;
    const int quad = lane >> 4, l16 = lane & 15;
    const int wm = (wid >> 1) * 32, wn = (wid & 1) * 64;

    const f32x4 fzero = {0.f, 0.f, 0.f, 0.f};
    f32x4 acc[2][4];
#pragma unroll
    for (int i = 0; i < 2; ++i)
#pragma unroll
        for (int j = 0; j < 4; ++j) acc[i][j] = fzero;

    const int arow = tid >> 2, ac = (tid & 3) * 16;   // A: 4 float4/thread
    const int brow = tid >> 1, bc = (tid & 1) * 32;   // B: 4 uint4/thread

    float4 ar[4];
    uint4  br[4];
    {
        const float* sa = &x[(size_t)(m0 + arow) * 1024 + ac];
#pragma unroll
        for (int q = 0; q < 4; ++q) ar[q] = *(const float4*)&sa[q * 4];
        const __bf16* sB = &Wb[(size_t)(n0 + brow) * 1024 + bc];
#pragma unroll
        for (int q = 0; q < 4; ++q) br[q] = *(const uint4*)&sB[q * 8];
    }

    for (int t = 0; t < 16; ++t) {
        const int buf = t & 1;
        {   // store staged regs (A: fp32 -> bf16)
            bf16x8 p0 = {(__bf16)ar[0].x, (__bf16)ar[0].y, (__bf16)ar[0].z, (__bf16)ar[0].w,
                         (__bf16)ar[1].x, (__bf16)ar[1].y, (__bf16)ar[1].z, (__bf16)ar[1].w};
            bf16x8 p1 = {(__bf16)ar[2].x, (__bf16)ar[2].y, (__bf16)ar[2].z, (__bf16)ar[2].w,
                         (__bf16)ar[3].x, (__bf16)ar[3].y, (__bf16)ar[3].z, (__bf16)ar[3].w};
            *(bf16x8*)&As[buf][arow][ac]     = p0;
            *(bf16x8*)&As[buf][arow][ac + 8] = p1;
#pragma unroll
            for (int q = 0; q < 4; ++q)
                *(uint4*)&Bs[buf][brow][bc + q * 8] = br[q];
        }
        __syncthreads();
        if (t < 15) {                       // prefetch t+1, consumed next iter
            const int kk = (t + 1) * 64;
            const float* sa = &x[(size_t)(m0 + arow) * 1024 + kk + ac];
#pragma unroll
            for (int q = 0; q < 4; ++q) ar[q] = *(const float4*)&sa[q * 4];
            const __bf16* sB = &Wb[(size_t)(n0 + brow) * 1024 + kk + bc];
#pragma unroll
            for (int q = 0; q < 4; ++q) br[q] = *(const uint4*)&sB[q * 8];
        }
#pragma unroll
        for (int ks = 0; ks < 2; ++ks) {
            const int k0 = ks * 32 + quad * 8;
            bf16x8 a[2], bb[4];
#pragma unroll
            for (int mt = 0; mt < 2; ++mt)
                a[mt] = *(const bf16x8*)&As[buf][wm + mt * 16 + l16][k0];
#pragma unroll
            for (int nt = 0; nt < 4; ++nt)
                bb[nt] = *(const bf16x8*)&Bs[buf][wn + nt * 16 + l16][k0];
#pragma unroll
            for (int mt = 0; mt < 2; ++mt)
#pragma unroll
                for (int nt = 0; nt < 4; ++nt)
                    acc[mt][nt] = MFMA16(a[mt], bb[nt], acc[mt][nt]);
        }
    }

    const float* bias = (which == 0) ? bq : (which == 1) ? bk : bv;
    if (which < 2) {
        __bf16* dst = (which == 0) ? Qb : Kb;
#pragma unroll
        for (int nt = 0; nt < 4; ++nt) {
            int col = wn + nt * 16 + l16;
            float bvv = bias[col];
#pragma unroll
            for (int mt = 0; mt < 2; ++mt)
#pragma unroll
                for (int r = 0; r < 4; ++r) {
                    int row = m0 + wm + mt * 16 + quad * 4 + r;
                    dst[(size_t)row * 128 + col] = (__bf16)(acc[mt][nt][r] + bvv);
                }
        }
    } else {
#pragma unroll
        for (int nt = 0; nt < 4; ++nt) {
            int col = wn + nt * 16 + l16;               // head index
            float bvv = bias[col];
#pragma unroll
            for (int mt = 0; mt < 2; ++mt) {
                int row = m0 + wm + mt * 16 + quad * 4;
                int bb_ = row >> 12, s = row & 4095;
                bf16x4 pk = {(__bf16)(acc[mt][nt][0] + bvv),
                             (__bf16)(acc[mt][nt][1] + bvv),
                             (__bf16)(acc[mt][nt][2] + bvv),
                             (__bf16)(acc[mt][nt][3] + bvv)};
                *(bf16x4*)&Vt[((size_t)(bb_ * 128 + col)) * 4096 + s] = pk;
            }
        }
    }
}

// -------------------------------------------------------------- flash_attn --
// v9: identical loop body to v8 (barrier-free, K/V frags direct from global,
// plT-only LDS) but runtime chunk size C (host-tiered by ws_size), 4 blocks/CU
// (launch_bounds(256,4); VGPR must stay <=128), setprio around MFMA clusters.
__global__ __launch_bounds__(256, 4) void flash_attn(
    const __bf16* __restrict__ Qb, const __bf16* __restrict__ Kb,
    const __bf16* __restrict__ Vt, const int* __restrict__ mask,
    float* __restrict__ out, float* __restrict__ ml, __bf16* __restrict__ pex,
    int C, int NS, int NPEX)
{
    __shared__ __align__(16) char smem[34816];
    __bf16 (*plT)[32][72] = (__bf16(*)[32][72])smem;   // [wave][q32][key64+pad]
    __bf16 (*OL)[136]     = (__bf16(*)[136])smem;      // epilogue overlay

    // ---- block -> (T, b, j): n(T)=ceil(2(T+1)/C) chunks of <=C key-iters ----
    int ii = blockIdx.x, T = 0, n, cum = 0, cumex = 0;
    for (;; ++T) {
        n = (2 * (T + 1) + C - 1) / C;
        if (ii < 4 * n) break;
        ii -= 4 * n;
        cum += n;                            // per-b slot prefix
        cumex += (n > 2) ? (n - 2) : 0;      // per-b pex prefix
    }
    const int b  = ii / n;
    const int j  = ii % n;
    const int nk = 2 * (T + 1);
    const int t0 = j * C;
    const int t1 = (nk < t0 + C) ? nk : (t0 + C);
    const int r0 = T * 128;
    const int slot = b * NS + cum + j;       // ml slot id

    const int tid = threadIdx.x, wid = tid >> 6, lane = tid & 63;
    const int quad = lane >> 4, l16 = lane & 15;
    const int qw = r0 + wid * 32;                      // wave's q base
    const size_t sb = (size_t)b * 4096;
    const float qs = 0.08838834764831845f * 1.4426950408889634f; // scale*log2e

    bf16x8 qf[2][4];                                   // Q B-frags, scale folded
#pragma unroll
    for (int nf = 0; nf < 2; ++nf)
#pragma unroll
        for (int ks = 0; ks < 4; ++ks) {
            qf[nf][ks] = *(const bf16x8*)
                &Qb[(sb + qw + nf * 16 + l16) * 128 + ks * 32 + quad * 8];
#pragma unroll
            for (int e = 0; e < 8; ++e)
                qf[nf][ks][e] = (__bf16)((float)qf[nf][ks][e] * qs);
        }

    float mi[2] = {-1e30f, -1e30f}, li[2] = {0.f, 0.f};
    const f32x4 fzero = {0.f, 0.f, 0.f, 0.f};
    f32x4 o[8][2];                                     // O^T: 8 head-frags x 2 q-frags
#pragma unroll
    for (int hf = 0; hf < 8; ++hf)
#pragma unroll
        for (int nf = 0; nf < 2; ++nf) o[hf][nf] = fzero;

    // per-lane fragment base pointers (global = fragment layout)
    const __bf16* kb = Kb + (sb + l16) * 128 + quad * 8;
    const __bf16* vb = Vt + ((size_t)b * 128 + l16) * 4096 + quad * 8;

    for (int t = t0; t < t1; ++t) {
        const int k0 = t * 64;
        const int mv = mask[sb + k0 + lane];

        // ---- S^T = K Q^T: rows=keys(64, 4 mf), cols=q(32, 2 nf) ----
        f32x4 s[4][2];
#pragma unroll
        for (int mf = 0; mf < 4; ++mf)
#pragma unroll
            for (int nf = 0; nf < 2; ++nf) s[mf][nf] = fzero;
        __builtin_amdgcn_s_setprio(1);
#pragma unroll
        for (int ks = 0; ks < 4; ++ks) {
            bf16x8 a[4];
#pragma unroll
            for (int mf = 0; mf < 4; ++mf)
                a[mf] = *(const bf16x8*)&kb[(size_t)(k0 + mf * 16) * 128 + ks * 32];
#pragma unroll
            for (int mf = 0; mf < 4; ++mf)
#pragma unroll
                for (int nf = 0; nf < 2; ++nf)
                    s[mf][nf] = MFMA16(a[mf], qf[nf][ks], s[mf][nf]);
        }
        __builtin_amdgcn_s_setprio(0);
        // prefetch PV first half's V frags above the softmax (hides L2 latency)
        bf16x8 va0[8];
#pragma unroll
        for (int hf = 0; hf < 8; ++hf)
            va0[hf] = *(const bf16x8*)&vb[(size_t)(hf * 16) * 4096 + k0];

        // ---- masking (C-layout: key = mf*16+quad*4+r, q = qw+nf*16+l16) ----
        unsigned long long mb = __ballot(mv != 0);
        if (mb != ~0ull || k0 + 63 > qw) {
#pragma unroll
            for (int mf = 0; mf < 4; ++mf)
#pragma unroll
                for (int r = 0; r < 4; ++r) {
                    int kl = mf * 16 + quad * 4 + r;
                    bool mok = (mb >> kl) & 1;
                    int kc = k0 + kl;
#pragma unroll
                    for (int nf = 0; nf < 2; ++nf) {
                        int q = qw + nf * 16 + l16;
                        bool ok = mok && (kc <= q);
                        s[mf][nf][r] = ok ? s[mf][nf][r] : -1e30f;
                    }
                }
        }
        // ---- online softmax per q (log2 domain; reduce over quads) ----
#pragma unroll
        for (int nf = 0; nf < 2; ++nf) {
            float mx = s[0][nf][0];
#pragma unroll
            for (int mf = 0; mf < 4; ++mf)
#pragma unroll
                for (int r = 0; r < 4; ++r) mx = fmaxf(mx, s[mf][nf][r]);
            mx = fmaxf(mx, __shfl_xor(mx, 16));
            mx = fmaxf(mx, __shfl_xor(mx, 32));
            float mnew  = fmaxf(mi[nf], mx);
            float alpha = EXP2F(mi[nf] - mnew);
            float rs = 0.f;
#pragma unroll
            for (int mf = 0; mf < 4; ++mf)
#pragma unroll
                for (int r = 0; r < 4; ++r) {
                    float sv = s[mf][nf][r];
                    float p = (sv < -5e29f) ? 0.f : EXP2F(sv - mnew);
                    s[mf][nf][r] = p;
                    rs += p;
                }
            rs += __shfl_xor(rs, 16);
            rs += __shfl_xor(rs, 32);
            li[nf] = li[nf] * alpha + rs;
            mi[nf] = mnew;
#pragma unroll
            for (int hf = 0; hf < 8; ++hf) {
                o[hf][nf][0] *= alpha; o[hf][nf][1] *= alpha;
                o[hf][nf][2] *= alpha; o[hf][nf][3] *= alpha;
            }
            // pack P (consecutive keys in-lane) -> b32 LDS writes
            int ql = nf * 16 + l16;
#pragma unroll
            for (int mf = 0; mf < 4; ++mf) {
                bf16x2 w0 = {(__bf16)s[mf][nf][0], (__bf16)s[mf][nf][1]};
                bf16x2 w1 = {(__bf16)s[mf][nf][2], (__bf16)s[mf][nf][3]};
                *(bf16x2*)&plT[wid][ql][mf * 16 + quad * 4]     = w0;
                *(bf16x2*)&plT[wid][ql][mf * 16 + quad * 4 + 2] = w1;
            }
        }
        asm volatile("s_waitcnt lgkmcnt(0)" ::: "memory"); // per-wave DS order
        // ---- O^T += V^T P^T (V frags straight from global) ----
        bf16x8 pb0[2], pb1[2];
#pragma unroll
        for (int nf = 0; nf < 2; ++nf) {
            pb0[nf] = *(const bf16x8*)&plT[wid][nf * 16 + l16][quad * 8];
            pb1[nf] = *(const bf16x8*)&plT[wid][nf * 16 + l16][32 + quad * 8];
        }
        bf16x8 va1[8];
#pragma unroll
        for (int hf = 0; hf < 8; ++hf)
            va1[hf] = *(const bf16x8*)&vb[(size_t)(hf * 16) * 4096 + k0 + 32];
        __builtin_amdgcn_s_setprio(1);
#pragma unroll
        for (int hf = 0; hf < 8; ++hf)
#pragma unroll
            for (int nf = 0; nf < 2; ++nf)
                o[hf][nf] = MFMA16(va0[hf], pb0[nf], o[hf][nf]);
#pragma unroll
        for (int hf = 0; hf < 8; ++hf)
#pragma unroll
            for (int nf = 0; nf < 2; ++nf)
                o[hf][nf] = MFMA16(va1[hf], pb1[nf], o[hf][nf]);
        __builtin_amdgcn_s_setprio(0);
    }

    // ---- epilogue: transpose O^T via LDS, coalesced bf16 partial store ----
    __syncthreads();                                   // plT dead; OL overlays
    float inv[2];
#pragma unroll
    for (int nf = 0; nf < 2; ++nf) inv[nf] = (li[nf] > 0.f) ? 1.0f / li[nf] : 0.f;
#pragma unroll
    for (int nf = 0; nf < 2; ++nf) {
        int ql = wid * 32 + nf * 16 + l16;
#pragma unroll
        for (int hf = 0; hf < 8; ++hf) {
            int hd = hf * 16 + quad * 4;
            bf16x2 w0 = {(__bf16)(o[hf][nf][0] * inv[nf]), (__bf16)(o[hf][nf][1] * inv[nf])};
            bf16x2 w1 = {(__bf16)(o[hf][nf][2] * inv[nf]), (__bf16)(o[hf][nf][3] * inv[nf])};
            *(bf16x2*)&OL[ql][hd]     = w0;
            *(bf16x2*)&OL[ql][hd + 2] = w1;
        }
        if (quad == 0) {
            size_t base = ((size_t)slot * 128 + ql) * 2;
            ml[base]     = mi[nf];
            ml[base + 1] = li[nf];
        }
    }
    __syncthreads();
    __bf16* dst = (j < 2)
        ? (__bf16*)((char*)out + (sb + r0) * 512 + (size_t)j * 32768)
        : pex + ((size_t)(b * NPEX + cumex + (j - 2))) * 16384;
    {
        int qrow = tid >> 1, cb2 = (tid & 1) * 64;
#pragma unroll
        for (int i = 0; i < 8; ++i) {
            bf16x8 v = *(const bf16x8*)&OL[qrow][cb2 + i * 8];
            *(bf16x8*)&dst[(size_t)qrow * 128 + cb2 + i * 8] = v;
        }
    }
}

// ----------------------------------------------------------------- mergeN ---
// One block per (b,T): combine n(T) pre-normalized bf16 partials (j<2 from
// the tile's own out rows, staged to regs before overwrite; j>=2 streamed from
// pex) into final fp32.
__global__ __launch_bounds__(256) void mergeN(
    float* __restrict__ out, const float* __restrict__ ml,
    const __bf16* __restrict__ pex, int C, int NS, int NPEX)
{
    const int T = blockIdx.x, b = blockIdx.y;
    int cum = 0, cumex = 0;
    for (int tt = 0; tt < T; ++tt) {
        int nn = (2 * (tt + 1) + C - 1) / C;
        cum += nn;
        cumex += (nn > 2) ? (nn - 2) : 0;
    }
    const int n  = (2 * (T + 1) + C - 1) / C;
    const int r0 = T * 128;
    const size_t sb = (size_t)b * 4096;
    const int ql = threadIdx.x >> 1, ch = (threadIdx.x & 1) * 64;
    const int slot0 = b * NS + cum;

    float mm = -1e30f;
    for (int jj = 0; jj < n; ++jj)
        mm = fmaxf(mm, ml[((size_t)(slot0 + jj) * 128 + ql) * 2]);

    // stage the (up to 2) in-out partials before overwriting out
    const __bf16* pout = (const __bf16*)((const char*)out + (sb + r0) * 512);
    bf16x8 rg0[8], rg1[8];
#pragma unroll
    for (int q2 = 0; q2 < 8; ++q2)
        rg0[q2] = *(const bf16x8*)&pout[(size_t)ql * 128 + ch + q2 * 8];
#pragma unroll
    for (int q2 = 0; q2 < 8; ++q2)
        rg1[q2] = *(const bf16x8*)&pout[16384 + (size_t)ql * 128 + ch + q2 * 8];
    __syncthreads();                                   // all reads done

    float acc[64];
#pragma unroll
    for (int k = 0; k < 64; ++k) acc[k] = 0.f;
    float den = 0.f;
    {   // j = 0 (always exists)
        size_t base = ((size_t)slot0 * 128 + ql) * 2;
        float m = ml[base], l = ml[base + 1];
        float w = (l > 0.f) ? EXP2F(m - mm) * l : 0.f;
        den += w;
#pragma unroll
        for (int q2 = 0; q2 < 8; ++q2)
#pragma unroll
            for (int e = 0; e < 8; ++e)
                acc[q2 * 8 + e] += w * (float)rg0[q2][e];
    }
    if (n > 1) {   // j = 1
        size_t base = ((size_t)(slot0 + 1) * 128 + ql) * 2;
        float m = ml[base], l = ml[base + 1];
        float w = (l > 0.f) ? EXP2F(m - mm) * l : 0.f;
        den += w;
#pragma unroll
        for (int q2 = 0; q2 < 8; ++q2)
#pragma unroll
            for (int e = 0; e < 8; ++e)
                acc[q2 * 8 + e] += w * (float)rg1[q2][e];
    }
    for (int jj = 2; jj < n; ++jj) {
        size_t base = ((size_t)(slot0 + jj) * 128 + ql) * 2;
        float m = ml[base], l = ml[base + 1];
        float w = (l > 0.f) ? EXP2F(m - mm) * l : 0.f;
        den += w;
        const __bf16* p = pex + ((size_t)(b * NPEX + cumex + (jj - 2))) * 16384
                        + (size_t)ql * 128 + ch;
#pragma unroll
        for (int q2 = 0; q2 < 8; ++q2) {
            bf16x8 v = *(const bf16x8*)&p[q2 * 8];
#pragma unroll
            for (int e = 0; e < 8; ++e)
                acc[q2 * 8 + e] += w * (float)v[e];
        }
    }
    float sc = (den > 0.f) ? 1.0f / den : 0.f;
    float* op = &out[(sb + r0 + ql) * 128 + ch];
#pragma unroll
    for (int q2 = 0; q2 < 8; ++q2) {
        float4 v0 = {acc[q2 * 8 + 0] * sc, acc[q2 * 8 + 1] * sc,
                     acc[q2 * 8 + 2] * sc, acc[q2 * 8 + 3] * sc};
        float4 v1 = {acc[q2 * 8 + 4] * sc, acc[q2 * 8 + 5] * sc,
                     acc[q2 * 8 + 6] * sc, acc[q2 * 8 + 7] * sc};
        *(float4*)&op[q2 * 8]     = v0;
        *(float4*)&op[q2 * 8 + 4] = v1;
    }
}

// ----------------------------------------------------------------- launch ---
extern "C" void kernel_launch(void* const* d_in, const int* in_sizes, int n_in,
                              void* d_out, int out_size, void* d_ws, size_t ws_size,
                              hipStream_t stream)
{
    const float* x    = (const float*)d_in[0];
    const int*   mask = (const int*)d_in[1];
    const float* Wq   = (const float*)d_in[2];
    const float* bq   = (const float*)d_in[3];
    const float* Wk   = (const float*)d_in[4];
    const float* bk   = (const float*)d_in[5];
    const float* Wv   = (const float*)d_in[6];
    const float* bv   = (const float*)d_in[7];
    float* out = (float*)d_out;

    char* ws = (char*)d_ws;
    __bf16* Qb  = (__bf16*)ws;                        // 4 MiB
    __bf16* Kb  = Qb + (size_t)16384 * 128;           // 4 MiB
    __bf16* Vt  = Kb + (size_t)16384 * 128;           // 4 MiB ([b][h][s])
    __bf16* Wb  = Vt + (size_t)16384 * 128;           // 768 KiB @ 12,582,912
    const size_t PEX_OFF = 13369344;

    // --- tier the chunk size by workspace capacity ---
    const int Cs[3] = {5, 6, 10};
    int C = 10, NS = 0, NPEX = 0;
    size_t mlOff = 0;
    for (int ci = 0; ci < 3; ++ci) {
        int c = Cs[ci], ns = 0, npex = 0;
        for (int T = 0; T < 32; ++T) {
            int n = (2 * (T + 1) + c - 1) / c;
            ns += n;
            npex += (n > 2) ? (n - 2) : 0;
        }
        size_t mlBytes  = (size_t)4 * ns * 1024;      // 4b x ns slots x 128q x 2 f32
        size_t pexBytes = (size_t)4 * npex * 32768;   // 4b x npex tiles x 128x128 bf16
        size_t mlo, tot;
        if (mlBytes <= 786432) { mlo = 12582912; tot = PEX_OFF + pexBytes; }
        else                   { mlo = PEX_OFF + pexBytes; tot = mlo + mlBytes; }
        if (tot <= ws_size || ci == 2) {
            C = c; NS = ns; NPEX = npex; mlOff = mlo;
            break;
        }
    }
    float*  ml  = (float*)(ws + mlOff);
    __bf16* pex = (__bf16*)(ws + PEX_OFF);

    prep_w<<<384, 256, 0, stream>>>(Wq, Wk, Wv, Wb);
    qkv_gemm<<<768, 256, 0, stream>>>(x, Wb, bq, bk, bv, Qb, Kb, Vt);
    flash_attn<<<4 * NS, 256, 0, stream>>>(Qb, Kb, Vt, mask, out, ml, pex, C, NS, NPEX);
    mergeN<<<dim3(32, 4), 256, 0, stream>>>(out, ml, pex, C, NS, NPEX);
}

// Round 3
// 298.503 us; speedup vs baseline: 1.2704x; 1.2704x over previous
//
#include <hip/hip_runtime.h>

// MaskedSelfAttention: B=4, S=4096, D=1024, H=128. fp32 in/out, bf16 MFMA compute.
// v10: v9 post-mortem: launch_bounds VGPR clamps (flash (256,4)->VGPR 64,
// qkv (256,3)->VGPR 68) caused catastrophic scratch spill (WRITE_SIZE 316MB /
// 119MB). Occupancy never needed the clamp: at VGPR 124 HW already allows
// 4 blocks/CU; v8's limiter was the 476-block grid (1.86 blocks/CU avg).
// v10 = v8 register regime + C=5 -> 896 uniform blocks (grid avg 3.5/CU).
// qkv: v8 body, pad 72->68 (0 bank conflicts measured in v9, 52.2KB -> 3
// blocks/CU by resources). Host tiers C by ws_size (C=5 needs 35.5MiB, ran
// in v9 => fits).

typedef __bf16 bf16x8 __attribute__((ext_vector_type(8)));
typedef __bf16 bf16x4 __attribute__((ext_vector_type(4)));
typedef __bf16 bf16x2 __attribute__((ext_vector_type(2)));
typedef float  f32x4  __attribute__((ext_vector_type(4)));

#define MFMA16(a, b, c) __builtin_amdgcn_mfma_f32_16x16x32_bf16(a, b, c, 0, 0, 0)
#define EXP2F(x) __builtin_amdgcn_exp2f(x)

// ---------------------------------------------------------------- prep_w ----
__global__ __launch_bounds__(256) void prep_w(
    const float* __restrict__ Wq, const float* __restrict__ Wk,
    const float* __restrict__ Wv, __bf16* __restrict__ Wb)
{
    int i = (blockIdx.x * 256 + threadIdx.x) * 4;
    int row = i >> 10;
    const float* W = (row < 128) ? Wq : (row < 256) ? Wk : Wv;
    float4 v = *(const float4*)&W[(size_t)(row & 127) * 1024 + (i & 1023)];
    bf16x4 pk = {(__bf16)v.x, (__bf16)v.y, (__bf16)v.z, (__bf16)v.w};
    *(bf16x4*)&Wb[i] = pk;
}

// -------------------------------------------------------------- qkv_gemm ----
// v10: v8 body (default launch_bounds -> no VGPR clamp), LDS pad 68 (row
// stride 136B == 2 banks mod 32: conflict-free, measured 0 in v9; 52.2KB ->
// 3 blocks/CU by resources). 1-D grid, which=bx%3 keeps the 3 QKV blocks of
// one x-slab dispatch-adjacent for L2 reuse of x.
__global__ __launch_bounds__(256) void qkv_gemm(
    const float* __restrict__ x, const __bf16* __restrict__ Wb,
    const float* __restrict__ bq, const float* __restrict__ bk,
    const float* __restrict__ bv,
    __bf16* __restrict__ Qb, __bf16* __restrict__ Kb, __bf16* __restrict__ Vt)
{
    __shared__ __bf16 As[2][64][68];
    __shared__ __bf16 Bs[2][128][68];

    const int tid   = threadIdx.x;
    const int bx    = blockIdx.x;
    const int which = bx % 3;               // 0=Q 1=K 2=V
    const int m0    = (bx / 3) * 64;
    const int n0    = which * 128;
    const int lane = tid & 63, wid = tid >> 6;
    const int quad = lane >> 4, l16 = lane & 15;
    const int wm = (wid >> 1) * 32, wn = (wid & 1) * 64;

    const f32x4 fzero = {0.f, 0.f, 0.f, 0.f};
    f32x4 acc[2][4];
#pragma unroll
    for (int i = 0; i < 2; ++i)
#pragma unroll
        for (int j = 0; j < 4; ++j) acc[i][j] = fzero;

    const int arow = tid >> 2, ac = (tid & 3) * 16;   // A: 4 float4/thread
    const int brow = tid >> 1, bc = (tid & 1) * 32;   // B: 4 uint4/thread

    float4 ar[4];
    uint4  br[4];
    {
        const float* sa = &x[(size_t)(m0 + arow) * 1024 + ac];
#pragma unroll
        for (int q = 0; q < 4; ++q) ar[q] = *(const float4*)&sa[q * 4];
        const __bf16* sB = &Wb[(size_t)(n0 + brow) * 1024 + bc];
#pragma unroll
        for (int q = 0; q < 4; ++q) br[q] = *(const uint4*)&sB[q * 8];
    }

    for (int t = 0; t < 16; ++t) {
        const int buf = t & 1;
        {   // store staged regs (A: fp32 -> bf16)
            bf16x8 p0 = {(__bf16)ar[0].x, (__bf16)ar[0].y, (__bf16)ar[0].z, (__bf16)ar[0].w,
                         (__bf16)ar[1].x, (__bf16)ar[1].y, (__bf16)ar[1].z, (__bf16)ar[1].w};
            bf16x8 p1 = {(__bf16)ar[2].x, (__bf16)ar[2].y, (__bf16)ar[2].z, (__bf16)ar[2].w,
                         (__bf16)ar[3].x, (__bf16)ar[3].y, (__bf16)ar[3].z, (__bf16)ar[3].w};
            *(bf16x8*)&As[buf][arow][ac]     = p0;
            *(bf16x8*)&As[buf][arow][ac + 8] = p1;
#pragma unroll
            for (int q = 0; q < 4; ++q)
                *(uint4*)&Bs[buf][brow][bc + q * 8] = br[q];
        }
        __syncthreads();
        if (t < 15) {                       // prefetch t+1, consumed next iter
            const int kk = (t + 1) * 64;
            const float* sa = &x[(size_t)(m0 + arow) * 1024 + kk + ac];
#pragma unroll
            for (int q = 0; q < 4; ++q) ar[q] = *(const float4*)&sa[q * 4];
            const __bf16* sB = &Wb[(size_t)(n0 + brow) * 1024 + kk + bc];
#pragma unroll
            for (int q = 0; q < 4; ++q) br[q] = *(const uint4*)&sB[q * 8];
        }
#pragma unroll
        for (int ks = 0; ks < 2; ++ks) {
            const int k0 = ks * 32 + quad * 8;
            bf16x8 a[2], bb[4];
#pragma unroll
            for (int mt = 0; mt < 2; ++mt)
                a[mt] = *(const bf16x8*)&As[buf][wm + mt * 16 + l16][k0];
#pragma unroll
            for (int nt = 0; nt < 4; ++nt)
                bb[nt] = *(const bf16x8*)&Bs[buf][wn + nt * 16 + l16][k0];
#pragma unroll
            for (int mt = 0; mt < 2; ++mt)
#pragma unroll
                for (int nt = 0; nt < 4; ++nt)
                    acc[mt][nt] = MFMA16(a[mt], bb[nt], acc[mt][nt]);
        }
    }

    const float* bias = (which == 0) ? bq : (which == 1) ? bk : bv;
    if (which < 2) {
        __bf16* dst = (which == 0) ? Qb : Kb;
#pragma unroll
        for (int nt = 0; nt < 4; ++nt) {
            int col = wn + nt * 16 + l16;
            float bvv = bias[col];
#pragma unroll
            for (int mt = 0; mt < 2; ++mt)
#pragma unroll
                for (int r = 0; r < 4; ++r) {
                    int row = m0 + wm + mt * 16 + quad * 4 + r;
                    dst[(size_t)row * 128 + col] = (__bf16)(acc[mt][nt][r] + bvv);
                }
        }
    } else {
#pragma unroll
        for (int nt = 0; nt < 4; ++nt) {
            int col = wn + nt * 16 + l16;               // head index
            float bvv = bias[col];
#pragma unroll
            for (int mt = 0; mt < 2; ++mt) {
                int row = m0 + wm + mt * 16 + quad * 4;
                int bb_ = row >> 12, s = row & 4095;
                bf16x4 pk = {(__bf16)(acc[mt][nt][0] + bvv),
                             (__bf16)(acc[mt][nt][1] + bvv),
                             (__bf16)(acc[mt][nt][2] + bvv),
                             (__bf16)(acc[mt][nt][3] + bvv)};
                *(bf16x4*)&Vt[((size_t)(bb_ * 128 + col)) * 4096 + s] = pk;
            }
        }
    }
}

// -------------------------------------------------------------- flash_attn --
// v10: v8 loop body (barrier-free, K/V frags direct from global, plT-only
// LDS, VGPR 124 via launch_bounds(256,2) -> HW runs 4 blocks/CU by
// resources), runtime chunk C, setprio around MFMA clusters.
__global__ __launch_bounds__(256, 2) void flash_attn(
    const __bf16* __restrict__ Qb, const __bf16* __restrict__ Kb,
    const __bf16* __restrict__ Vt, const int* __restrict__ mask,
    float* __restrict__ out, float* __restrict__ ml, __bf16* __restrict__ pex,
    int C, int NS, int NPEX)
{
    __shared__ __align__(16) char smem[34816];
    __bf16 (*plT)[32][72] = (__bf16(*)[32][72])smem;   // [wave][q32][key64+pad]
    __bf16 (*OL)[136]     = (__bf16(*)[136])smem;      // epilogue overlay

    // ---- block -> (T, b, j): n(T)=ceil(2(T+1)/C) chunks of <=C key-iters ----
    int ii = blockIdx.x, T = 0, n, cum = 0, cumex = 0;
    for (;; ++T) {
        n = (2 * (T + 1) + C - 1) / C;
        if (ii < 4 * n) break;
        ii -= 4 * n;
        cum += n;                            // per-b slot prefix
        cumex += (n > 2) ? (n - 2) : 0;      // per-b pex prefix
    }
    const int b  = ii / n;
    const int j  = ii % n;
    const int nk = 2 * (T + 1);
    const int t0 = j * C;
    const int t1 = (nk < t0 + C) ? nk : (t0 + C);
    const int r0 = T * 128;
    const int slot = b * NS + cum + j;       // ml slot id

    const int tid = threadIdx.x, wid = tid >> 6, lane = tid & 63;
    const int quad = lane >> 4, l16 = lane & 15;
    const int qw = r0 + wid * 32;                      // wave's q base
    const size_t sb = (size_t)b * 4096;
    const float qs = 0.08838834764831845f * 1.4426950408889634f; // scale*log2e

    bf16x8 qf[2][4];                                   // Q B-frags, scale folded
#pragma unroll
    for (int nf = 0; nf < 2; ++nf)
#pragma unroll
        for (int ks = 0; ks < 4; ++ks) {
            qf[nf][ks] = *(const bf16x8*)
                &Qb[(sb + qw + nf * 16 + l16) * 128 + ks * 32 + quad * 8];
#pragma unroll
            for (int e = 0; e < 8; ++e)
                qf[nf][ks][e] = (__bf16)((float)qf[nf][ks][e] * qs);
        }

    float mi[2] = {-1e30f, -1e30f}, li[2] = {0.f, 0.f};
    const f32x4 fzero = {0.f, 0.f, 0.f, 0.f};
    f32x4 o[8][2];                                     // O^T: 8 head-frags x 2 q-frags
#pragma unroll
    for (int hf = 0; hf < 8; ++hf)
#pragma unroll
        for (int nf = 0; nf < 2; ++nf) o[hf][nf] = fzero;

    // per-lane fragment base pointers (global = fragment layout)
    const __bf16* kb = Kb + (sb + l16) * 128 + quad * 8;
    const __bf16* vb = Vt + ((size_t)b * 128 + l16) * 4096 + quad * 8;

    for (int t = t0; t < t1; ++t) {
        const int k0 = t * 64;
        const int mv = mask[sb + k0 + lane];

        // ---- S^T = K Q^T: rows=keys(64, 4 mf), cols=q(32, 2 nf) ----
        f32x4 s[4][2];
#pragma unroll
        for (int mf = 0; mf < 4; ++mf)
#pragma unroll
            for (int nf = 0; nf < 2; ++nf) s[mf][nf] = fzero;
        __builtin_amdgcn_s_setprio(1);
#pragma unroll
        for (int ks = 0; ks < 4; ++ks) {
            bf16x8 a[4];
#pragma unroll
            for (int mf = 0; mf < 4; ++mf)
                a[mf] = *(const bf16x8*)&kb[(size_t)(k0 + mf * 16) * 128 + ks * 32];
#pragma unroll
            for (int mf = 0; mf < 4; ++mf)
#pragma unroll
                for (int nf = 0; nf < 2; ++nf)
                    s[mf][nf] = MFMA16(a[mf], qf[nf][ks], s[mf][nf]);
        }
        __builtin_amdgcn_s_setprio(0);
        // prefetch PV first half's V frags above the softmax (hides L2 latency)
        bf16x8 va0[8];
#pragma unroll
        for (int hf = 0; hf < 8; ++hf)
            va0[hf] = *(const bf16x8*)&vb[(size_t)(hf * 16) * 4096 + k0];

        // ---- masking (C-layout: key = mf*16+quad*4+r, q = qw+nf*16+l16) ----
        unsigned long long mb = __ballot(mv != 0);
        if (mb != ~0ull || k0 + 63 > qw) {
#pragma unroll
            for (int mf = 0; mf < 4; ++mf)
#pragma unroll
                for (int r = 0; r < 4; ++r) {
                    int kl = mf * 16 + quad * 4 + r;
                    bool mok = (mb >> kl) & 1;
                    int kc = k0 + kl;
#pragma unroll
                    for (int nf = 0; nf < 2; ++nf) {
                        int q = qw + nf * 16 + l16;
                        bool ok = mok && (kc <= q);
                        s[mf][nf][r] = ok ? s[mf][nf][r] : -1e30f;
                    }
                }
        }
        // ---- online softmax per q (log2 domain; reduce over quads) ----
#pragma unroll
        for (int nf = 0; nf < 2; ++nf) {
            float mx = s[0][nf][0];
#pragma unroll
            for (int mf = 0; mf < 4; ++mf)
#pragma unroll
                for (int r = 0; r < 4; ++r) mx = fmaxf(mx, s[mf][nf][r]);
            mx = fmaxf(mx, __shfl_xor(mx, 16));
            mx = fmaxf(mx, __shfl_xor(mx, 32));
            float mnew  = fmaxf(mi[nf], mx);
            float alpha = EXP2F(mi[nf] - mnew);
            float rs = 0.f;
#pragma unroll
            for (int mf = 0; mf < 4; ++mf)
#pragma unroll
                for (int r = 0; r < 4; ++r) {
                    float sv = s[mf][nf][r];
                    float p = (sv < -5e29f) ? 0.f : EXP2F(sv - mnew);
                    s[mf][nf][r] = p;
                    rs += p;
                }
            rs += __shfl_xor(rs, 16);
            rs += __shfl_xor(rs, 32);
            li[nf] = li[nf] * alpha + rs;
            mi[nf] = mnew;
#pragma unroll
            for (int hf = 0; hf < 8; ++hf) {
                o[hf][nf][0] *= alpha; o[hf][nf][1] *= alpha;
                o[hf][nf][2] *= alpha; o[hf][nf][3] *= alpha;
            }
            // pack P (consecutive keys in-lane) -> b32 LDS writes
            int ql = nf * 16 + l16;
#pragma unroll
            for (int mf = 0; mf < 4; ++mf) {
                bf16x2 w0 = {(__bf16)s[mf][nf][0], (__bf16)s[mf][nf][1]};
                bf16x2 w1 = {(__bf16)s[mf][nf][2], (__bf16)s[mf][nf][3]};
                *(bf16x2*)&plT[wid][ql][mf * 16 + quad * 4]     = w0;
                *(bf16x2*)&plT[wid][ql][mf * 16 + quad * 4 + 2] = w1;
            }
        }
        asm volatile("s_waitcnt lgkmcnt(0)" ::: "memory"); // per-wave DS order
        // ---- O^T += V^T P^T (V frags straight from global) ----
        bf16x8 pb0[2], pb1[2];
#pragma unroll
        for (int nf = 0; nf < 2; ++nf) {
            pb0[nf] = *(const bf16x8*)&plT[wid][nf * 16 + l16][quad * 8];
            pb1[nf] = *(const bf16x8*)&plT[wid][nf * 16 + l16][32 + quad * 8];
        }
        bf16x8 va1[8];
#pragma unroll
        for (int hf = 0; hf < 8; ++hf)
            va1[hf] = *(const bf16x8*)&vb[(size_t)(hf * 16) * 4096 + k0 + 32];
        __builtin_amdgcn_s_setprio(1);
#pragma unroll
        for (int hf = 0; hf < 8; ++hf)
#pragma unroll
            for (int nf = 0; nf < 2; ++nf)
                o[hf][nf] = MFMA16(va0[hf], pb0[nf], o[hf][nf]);
#pragma unroll
        for (int hf = 0; hf < 8; ++hf)
#pragma unroll
            for (int nf = 0; nf < 2; ++nf)
                o[hf][nf] = MFMA16(va1[hf], pb1[nf], o[hf][nf]);
        __builtin_amdgcn_s_setprio(0);
    }

    // ---- epilogue: transpose O^T via LDS, coalesced bf16 partial store ----
    __syncthreads();                                   // plT dead; OL overlays
    float inv[2];
#pragma unroll
    for (int nf = 0; nf < 2; ++nf) inv[nf] = (li[nf] > 0.f) ? 1.0f / li[nf] : 0.f;
#pragma unroll
    for (int nf = 0; nf < 2; ++nf) {
        int ql = wid * 32 + nf * 16 + l16;
#pragma unroll
        for (int hf = 0; hf < 8; ++hf) {
            int hd = hf * 16 + quad * 4;
            bf16x2 w0 = {(__bf16)(o[hf][nf][0] * inv[nf]), (__bf16)(o[hf][nf][1] * inv[nf])};
            bf16x2 w1 = {(__bf16)(o[hf][nf][2] * inv[nf]), (__bf16)(o[hf][nf][3] * inv[nf])};
            *(bf16x2*)&OL[ql][hd]     = w0;
            *(bf16x2*)&OL[ql][hd + 2] = w1;
        }
        if (quad == 0) {
            size_t base = ((size_t)slot * 128 + ql) * 2;
            ml[base]     = mi[nf];
            ml[base + 1] = li[nf];
        }
    }
    __syncthreads();
    __bf16* dst = (j < 2)
        ? (__bf16*)((char*)out + (sb + r0) * 512 + (size_t)j * 32768)
        : pex + ((size_t)(b * NPEX + cumex + (j - 2))) * 16384;
    {
        int qrow = tid >> 1, cb2 = (tid & 1) * 64;
#pragma unroll
        for (int i = 0; i < 8; ++i) {
            bf16x8 v = *(const bf16x8*)&OL[qrow][cb2 + i * 8];
            *(bf16x8*)&dst[(size_t)qrow * 128 + cb2 + i * 8] = v;
        }
    }
}

// ----------------------------------------------------------------- mergeN ---
// One block per (b,T): combine n(T) pre-normalized bf16 partials (j<2 from
// the tile's own out rows, staged to regs before overwrite; j>=2 streamed from
// pex) into final fp32.
__global__ __launch_bounds__(256) void mergeN(
    float* __restrict__ out, const float* __restrict__ ml,
    const __bf16* __restrict__ pex, int C, int NS, int NPEX)
{
    const int T = blockIdx.x, b = blockIdx.y;
    int cum = 0, cumex = 0;
    for (int tt = 0; tt < T; ++tt) {
        int nn = (2 * (tt + 1) + C - 1) / C;
        cum += nn;
        cumex += (nn > 2) ? (nn - 2) : 0;
    }
    const int n  = (2 * (T + 1) + C - 1) / C;
    const int r0 = T * 128;
    const size_t sb = (size_t)b * 4096;
    const int ql = threadIdx.x >> 1, ch = (threadIdx.x & 1) * 64;
    const int slot0 = b * NS + cum;

    float mm = -1e30f;
    for (int jj = 0; jj < n; ++jj)
        mm = fmaxf(mm, ml[((size_t)(slot0 + jj) * 128 + ql) * 2]);

    // stage the (up to 2) in-out partials before overwriting out
    const __bf16* pout = (const __bf16*)((const char*)out + (sb + r0) * 512);
    bf16x8 rg0[8], rg1[8];
#pragma unroll
    for (int q2 = 0; q2 < 8; ++q2)
        rg0[q2] = *(const bf16x8*)&pout[(size_t)ql * 128 + ch + q2 * 8];
#pragma unroll
    for (int q2 = 0; q2 < 8; ++q2)
        rg1[q2] = *(const bf16x8*)&pout[16384 + (size_t)ql * 128 + ch + q2 * 8];
    __syncthreads();                                   // all reads done

    float acc[64];
#pragma unroll
    for (int k = 0; k < 64; ++k) acc[k] = 0.f;
    float den = 0.f;
    {   // j = 0 (always exists)
        size_t base = ((size_t)slot0 * 128 + ql) * 2;
        float m = ml[base], l = ml[base + 1];
        float w = (l > 0.f) ? EXP2F(m - mm) * l : 0.f;
        den += w;
#pragma unroll
        for (int q2 = 0; q2 < 8; ++q2)
#pragma unroll
            for (int e = 0; e < 8; ++e)
                acc[q2 * 8 + e] += w * (float)rg0[q2][e];
    }
    if (n > 1) {   // j = 1
        size_t base = ((size_t)(slot0 + 1) * 128 + ql) * 2;
        float m = ml[base], l = ml[base + 1];
        float w = (l > 0.f) ? EXP2F(m - mm) * l : 0.f;
        den += w;
#pragma unroll
        for (int q2 = 0; q2 < 8; ++q2)
#pragma unroll
            for (int e = 0; e < 8; ++e)
                acc[q2 * 8 + e] += w * (float)rg1[q2][e];
    }
    for (int jj = 2; jj < n; ++jj) {
        size_t base = ((size_t)(slot0 + jj) * 128 + ql) * 2;
        float m = ml[base], l = ml[base + 1];
        float w = (l > 0.f) ? EXP2F(m - mm) * l : 0.f;
        den += w;
        const __bf16* p = pex + ((size_t)(b * NPEX + cumex + (jj - 2))) * 16384
                        + (size_t)ql * 128 + ch;
#pragma unroll
        for (int q2 = 0; q2 < 8; ++q2) {
            bf16x8 v = *(const bf16x8*)&p[q2 * 8];
#pragma unroll
            for (int e = 0; e < 8; ++e)
                acc[q2 * 8 + e] += w * (float)v[e];
        }
    }
    float sc = (den > 0.f) ? 1.0f / den : 0.f;
    float* op = &out[(sb + r0 + ql) * 128 + ch];
#pragma unroll
    for (int q2 = 0; q2 < 8; ++q2) {
        float4 v0 = {acc[q2 * 8 + 0] * sc, acc[q2 * 8 + 1] * sc,
                     acc[q2 * 8 + 2] * sc, acc[q2 * 8 + 3] * sc};
        float4 v1 = {acc[q2 * 8 + 4] * sc, acc[q2 * 8 + 5] * sc,
                     acc[q2 * 8 + 6] * sc, acc[q2 * 8 + 7] * sc};
        *(float4*)&op[q2 * 8]     = v0;
        *(float4*)&op[q2 * 8 + 4] = v1;
    }
}

// ----------------------------------------------------------------- launch ---
extern "C" void kernel_launch(void* const* d_in, const int* in_sizes, int n_in,
                              void* d_out, int out_size, void* d_ws, size_t ws_size,
                              hipStream_t stream)
{
    const float* x    = (const float*)d_in[0];
    const int*   mask = (const int*)d_in[1];
    const float* Wq   = (const float*)d_in[2];
    const float* bq   = (const float*)d_in[3];
    const float* Wk   = (const float*)d_in[4];
    const float* bk   = (const float*)d_in[5];
    const float* Wv   = (const float*)d_in[6];
    const float* bv   = (const float*)d_in[7];
    float* out = (float*)d_out;

    char* ws = (char*)d_ws;
    __bf16* Qb  = (__bf16*)ws;                        // 4 MiB
    __bf16* Kb  = Qb + (size_t)16384 * 128;           // 4 MiB
    __bf16* Vt  = Kb + (size_t)16384 * 128;           // 4 MiB ([b][h][s])
    __bf16* Wb  = Vt + (size_t)16384 * 128;           // 768 KiB @ 12,582,912
    const size_t PEX_OFF = 13369344;

    // --- tier the chunk size by workspace capacity ---
    const int Cs[3] = {5, 6, 10};
    int C = 10, NS = 0, NPEX = 0;
    size_t mlOff = 0;
    for (int ci = 0; ci < 3; ++ci) {
        int c = Cs[ci], ns = 0, npex = 0;
        for (int T = 0; T < 32; ++T) {
            int n = (2 * (T + 1) + c - 1) / c;
            ns += n;
            npex += (n > 2) ? (n - 2) : 0;
        }
        size_t mlBytes  = (size_t)4 * ns * 1024;      // 4b x ns slots x 128q x 2 f32
        size_t pexBytes = (size_t)4 * npex * 32768;   // 4b x npex tiles x 128x128 bf16
        size_t mlo, tot;
        if (mlBytes <= 786432) { mlo = 12582912; tot = PEX_OFF + pexBytes; }
        else                   { mlo = PEX_OFF + pexBytes; tot = mlo + mlBytes; }
        if (tot <= ws_size || ci == 2) {
            C = c; NS = ns; NPEX = npex; mlOff = mlo;
            break;
        }
    }
    float*  ml  = (float*)(ws + mlOff);
    __bf16* pex = (__bf16*)(ws + PEX_OFF);

    prep_w<<<384, 256, 0, stream>>>(Wq, Wk, Wv, Wb);
    qkv_gemm<<<768, 256, 0, stream>>>(x, Wb, bq, bk, bv, Qb, Kb, Vt);
    flash_attn<<<4 * NS, 256, 0, stream>>>(Qb, Kb, Vt, mask, out, ml, pex, C, NS, NPEX);
    mergeN<<<dim3(32, 4), 256, 0, stream>>>(out, ml, pex, C, NS, NPEX);
}

// Round 4
// 294.753 us; speedup vs baseline: 1.2865x; 1.0127x over previous
//
#include <hip/hip_runtime.h>

// MaskedSelfAttention: B=4, S=4096, D=1024, H=128. fp32 in/out, bf16 MFMA compute.
// v11: kill the scratch spills. v10 PMC: qkv_gemm VGPR=68, WRITE_SIZE=167MB
// (legit ~13MB) -> the DEFAULT launch_bounds(256) RA heuristic clamps to ~68
// VGPR and spills ~150MB/dispatch; pad 68's 3-blocks/CU made the scratch
// working set thrash L2 (96us vs ~60 at 2 blocks). flash with (256,2) compiles
// healthy at 124 VGPR -> apply (256,2) to qkv_gemm and mergeN (acc[64]+rg[16]
// ~ 150 regs, same latent spill). Restore v9's XCD slab grouping for qkv
// (measured FETCH 40.8MB vs 113MB with bx%3). flash unchanged from v10.

typedef __bf16 bf16x8 __attribute__((ext_vector_type(8)));
typedef __bf16 bf16x4 __attribute__((ext_vector_type(4)));
typedef __bf16 bf16x2 __attribute__((ext_vector_type(2)));
typedef float  f32x4  __attribute__((ext_vector_type(4)));

#define MFMA16(a, b, c) __builtin_amdgcn_mfma_f32_16x16x32_bf16(a, b, c, 0, 0, 0)
#define EXP2F(x) __builtin_amdgcn_exp2f(x)

// ---------------------------------------------------------------- prep_w ----
__global__ __launch_bounds__(256) void prep_w(
    const float* __restrict__ Wq, const float* __restrict__ Wk,
    const float* __restrict__ Wv, __bf16* __restrict__ Wb)
{
    int i = (blockIdx.x * 256 + threadIdx.x) * 4;
    int row = i >> 10;
    const float* W = (row < 128) ? Wq : (row < 256) ? Wk : Wv;
    float4 v = *(const float4*)&W[(size_t)(row & 127) * 1024 + (i & 1023)];
    bf16x4 pk = {(__bf16)v.x, (__bf16)v.y, (__bf16)v.z, (__bf16)v.w};
    *(bf16x4*)&Wb[i] = pk;
}

// -------------------------------------------------------------- qkv_gemm ----
// v11: (256,2) -> RA budget 256 VGPR, no spill (pattern proven on flash).
// XCD slab grouping (v9, measured FETCH 40.8MB): the 3 QKV blocks of one
// x-slab land on the same XCD's L2. LDS pad 68 (0 conflicts measured), 52.2KB
// -> up to 3 blocks/CU by LDS once VGPR fits.
__global__ __launch_bounds__(256, 2) void qkv_gemm(
    const float* __restrict__ x, const __bf16* __restrict__ Wb,
    const float* __restrict__ bq, const float* __restrict__ bk,
    const float* __restrict__ bv,
    __bf16* __restrict__ Qb, __bf16* __restrict__ Kb, __bf16* __restrict__ Vt)
{
    __shared__ __bf16 As[2][64][68];
    __shared__ __bf16 Bs[2][128][68];

    const int tid   = threadIdx.x;
    const int bx    = blockIdx.x;
    const int xcd   = bx & 7, w8 = bx >> 3;   // 96 blocks per xcd
    const int slab  = xcd * 32 + w8 / 3;      // 0..255
    const int which = w8 % 3;                 // 0=Q 1=K 2=V
    const int m0    = slab * 64;
    const int n0    = which * 128;
    const int lane = tid & 63, wid = tid >> 6;
    const int quad = lane >> 4, l16 = lane & 15;
    const int wm = (wid >> 1) * 32, wn = (wid & 1) * 64;

    const f32x4 fzero = {0.f, 0.f, 0.f, 0.f};
    f32x4 acc[2][4];
#pragma unroll
    for (int i = 0; i < 2; ++i)
#pragma unroll
        for (int j = 0; j < 4; ++j) acc[i][j] = fzero;

    const int arow = tid >> 2, ac = (tid & 3) * 16;   // A: 4 float4/thread
    const int brow = tid >> 1, bc = (tid & 1) * 32;   // B: 4 uint4/thread

    float4 ar[4];
    uint4  br[4];
    {
        const float* sa = &x[(size_t)(m0 + arow) * 1024 + ac];
#pragma unroll
        for (int q = 0; q < 4; ++q) ar[q] = *(const float4*)&sa[q * 4];
        const __bf16* sB = &Wb[(size_t)(n0 + brow) * 1024 + bc];
#pragma unroll
        for (int q = 0; q < 4; ++q) br[q] = *(const uint4*)&sB[q * 8];
    }

    for (int t = 0; t < 16; ++t) {
        const int buf = t & 1;
        {   // store staged regs (A: fp32 -> bf16)
            bf16x8 p0 = {(__bf16)ar[0].x, (__bf16)ar[0].y, (__bf16)ar[0].z, (__bf16)ar[0].w,
                         (__bf16)ar[1].x, (__bf16)ar[1].y, (__bf16)ar[1].z, (__bf16)ar[1].w};
            bf16x8 p1 = {(__bf16)ar[2].x, (__bf16)ar[2].y, (__bf16)ar[2].z, (__bf16)ar[2].w,
                         (__bf16)ar[3].x, (__bf16)ar[3].y, (__bf16)ar[3].z, (__bf16)ar[3].w};
            *(bf16x8*)&As[buf][arow][ac]     = p0;
            *(bf16x8*)&As[buf][arow][ac + 8] = p1;
#pragma unroll
            for (int q = 0; q < 4; ++q)
                *(uint4*)&Bs[buf][brow][bc + q * 8] = br[q];
        }
        __syncthreads();
        if (t < 15) {                       // prefetch t+1, consumed next iter
            const int kk = (t + 1) * 64;
            const float* sa = &x[(size_t)(m0 + arow) * 1024 + kk + ac];
#pragma unroll
            for (int q = 0; q < 4; ++q) ar[q] = *(const float4*)&sa[q * 4];
            const __bf16* sB = &Wb[(size_t)(n0 + brow) * 1024 + kk + bc];
#pragma unroll
            for (int q = 0; q < 4; ++q) br[q] = *(const uint4*)&sB[q * 8];
        }
#pragma unroll
        for (int ks = 0; ks < 2; ++ks) {
            const int k0 = ks * 32 + quad * 8;
            bf16x8 a[2], bb[4];
#pragma unroll
            for (int mt = 0; mt < 2; ++mt)
                a[mt] = *(const bf16x8*)&As[buf][wm + mt * 16 + l16][k0];
#pragma unroll
            for (int nt = 0; nt < 4; ++nt)
                bb[nt] = *(const bf16x8*)&Bs[buf][wn + nt * 16 + l16][k0];
#pragma unroll
            for (int mt = 0; mt < 2; ++mt)
#pragma unroll
                for (int nt = 0; nt < 4; ++nt)
                    acc[mt][nt] = MFMA16(a[mt], bb[nt], acc[mt][nt]);
        }
    }

    const float* bias = (which == 0) ? bq : (which == 1) ? bk : bv;
    if (which < 2) {
        __bf16* dst = (which == 0) ? Qb : Kb;
#pragma unroll
        for (int nt = 0; nt < 4; ++nt) {
            int col = wn + nt * 16 + l16;
            float bvv = bias[col];
#pragma unroll
            for (int mt = 0; mt < 2; ++mt)
#pragma unroll
                for (int r = 0; r < 4; ++r) {
                    int row = m0 + wm + mt * 16 + quad * 4 + r;
                    dst[(size_t)row * 128 + col] = (__bf16)(acc[mt][nt][r] + bvv);
                }
        }
    } else {
#pragma unroll
        for (int nt = 0; nt < 4; ++nt) {
            int col = wn + nt * 16 + l16;               // head index
            float bvv = bias[col];
#pragma unroll
            for (int mt = 0; mt < 2; ++mt) {
                int row = m0 + wm + mt * 16 + quad * 4;
                int bb_ = row >> 12, s = row & 4095;
                bf16x4 pk = {(__bf16)(acc[mt][nt][0] + bvv),
                             (__bf16)(acc[mt][nt][1] + bvv),
                             (__bf16)(acc[mt][nt][2] + bvv),
                             (__bf16)(acc[mt][nt][3] + bvv)};
                *(bf16x4*)&Vt[((size_t)(bb_ * 128 + col)) * 4096 + s] = pk;
            }
        }
    }
}

// -------------------------------------------------------------- flash_attn --
// v10 loop body unchanged: barrier-free, K/V frags direct from global
// (fragment layout == memory layout), plT-only LDS, runtime chunk C,
// setprio around MFMA clusters. (256,2): VGPR 124, 4 blocks/CU by resources.
__global__ __launch_bounds__(256, 2) void flash_attn(
    const __bf16* __restrict__ Qb, const __bf16* __restrict__ Kb,
    const __bf16* __restrict__ Vt, const int* __restrict__ mask,
    float* __restrict__ out, float* __restrict__ ml, __bf16* __restrict__ pex,
    int C, int NS, int NPEX)
{
    __shared__ __align__(16) char smem[34816];
    __bf16 (*plT)[32][72] = (__bf16(*)[32][72])smem;   // [wave][q32][key64+pad]
    __bf16 (*OL)[136]     = (__bf16(*)[136])smem;      // epilogue overlay

    // ---- block -> (T, b, j): n(T)=ceil(2(T+1)/C) chunks of <=C key-iters ----
    int ii = blockIdx.x, T = 0, n, cum = 0, cumex = 0;
    for (;; ++T) {
        n = (2 * (T + 1) + C - 1) / C;
        if (ii < 4 * n) break;
        ii -= 4 * n;
        cum += n;                            // per-b slot prefix
        cumex += (n > 2) ? (n - 2) : 0;      // per-b pex prefix
    }
    const int b  = ii / n;
    const int j  = ii % n;
    const int nk = 2 * (T + 1);
    const int t0 = j * C;
    const int t1 = (nk < t0 + C) ? nk : (t0 + C);
    const int r0 = T * 128;
    const int slot = b * NS + cum + j;       // ml slot id

    const int tid = threadIdx.x, wid = tid >> 6, lane = tid & 63;
    const int quad = lane >> 4, l16 = lane & 15;
    const int qw = r0 + wid * 32;                      // wave's q base
    const size_t sb = (size_t)b * 4096;
    const float qs = 0.08838834764831845f * 1.4426950408889634f; // scale*log2e

    bf16x8 qf[2][4];                                   // Q B-frags, scale folded
#pragma unroll
    for (int nf = 0; nf < 2; ++nf)
#pragma unroll
        for (int ks = 0; ks < 4; ++ks) {
            qf[nf][ks] = *(const bf16x8*)
                &Qb[(sb + qw + nf * 16 + l16) * 128 + ks * 32 + quad * 8];
#pragma unroll
            for (int e = 0; e < 8; ++e)
                qf[nf][ks][e] = (__bf16)((float)qf[nf][ks][e] * qs);
        }

    float mi[2] = {-1e30f, -1e30f}, li[2] = {0.f, 0.f};
    const f32x4 fzero = {0.f, 0.f, 0.f, 0.f};
    f32x4 o[8][2];                                     // O^T: 8 head-frags x 2 q-frags
#pragma unroll
    for (int hf = 0; hf < 8; ++hf)
#pragma unroll
        for (int nf = 0; nf < 2; ++nf) o[hf][nf] = fzero;

    // per-lane fragment base pointers (global = fragment layout)
    const __bf16* kb = Kb + (sb + l16) * 128 + quad * 8;
    const __bf16* vb = Vt + ((size_t)b * 128 + l16) * 4096 + quad * 8;

    for (int t = t0; t < t1; ++t) {
        const int k0 = t * 64;
        const int mv = mask[sb + k0 + lane];

        // ---- S^T = K Q^T: rows=keys(64, 4 mf), cols=q(32, 2 nf) ----
        f32x4 s[4][2];
#pragma unroll
        for (int mf = 0; mf < 4; ++mf)
#pragma unroll
            for (int nf = 0; nf < 2; ++nf) s[mf][nf] = fzero;
        __builtin_amdgcn_s_setprio(1);
#pragma unroll
        for (int ks = 0; ks < 4; ++ks) {
            bf16x8 a[4];
#pragma unroll
            for (int mf = 0; mf < 4; ++mf)
                a[mf] = *(const bf16x8*)&kb[(size_t)(k0 + mf * 16) * 128 + ks * 32];
#pragma unroll
            for (int mf = 0; mf < 4; ++mf)
#pragma unroll
                for (int nf = 0; nf < 2; ++nf)
                    s[mf][nf] = MFMA16(a[mf], qf[nf][ks], s[mf][nf]);
        }
        __builtin_amdgcn_s_setprio(0);
        // prefetch PV first half's V frags above the softmax (hides L2 latency)
        bf16x8 va0[8];
#pragma unroll
        for (int hf = 0; hf < 8; ++hf)
            va0[hf] = *(const bf16x8*)&vb[(size_t)(hf * 16) * 4096 + k0];

        // ---- masking (C-layout: key = mf*16+quad*4+r, q = qw+nf*16+l16) ----
        unsigned long long mb = __ballot(mv != 0);
        if (mb != ~0ull || k0 + 63 > qw) {
#pragma unroll
            for (int mf = 0; mf < 4; ++mf)
#pragma unroll
                for (int r = 0; r < 4; ++r) {
                    int kl = mf * 16 + quad * 4 + r;
                    bool mok = (mb >> kl) & 1;
                    int kc = k0 + kl;
#pragma unroll
                    for (int nf = 0; nf < 2; ++nf) {
                        int q = qw + nf * 16 + l16;
                        bool ok = mok && (kc <= q);
                        s[mf][nf][r] = ok ? s[mf][nf][r] : -1e30f;
                    }
                }
        }
        // ---- online softmax per q (log2 domain; reduce over quads) ----
#pragma unroll
        for (int nf = 0; nf < 2; ++nf) {
            float mx = s[0][nf][0];
#pragma unroll
            for (int mf = 0; mf < 4; ++mf)
#pragma unroll
                for (int r = 0; r < 4; ++r) mx = fmaxf(mx, s[mf][nf][r]);
            mx = fmaxf(mx, __shfl_xor(mx, 16));
            mx = fmaxf(mx, __shfl_xor(mx, 32));
            float mnew  = fmaxf(mi[nf], mx);
            float alpha = EXP2F(mi[nf] - mnew);
            float rs = 0.f;
#pragma unroll
            for (int mf = 0; mf < 4; ++mf)
#pragma unroll
                for (int r = 0; r < 4; ++r) {
                    float sv = s[mf][nf][r];
                    float p = (sv < -5e29f) ? 0.f : EXP2F(sv - mnew);
                    s[mf][nf][r] = p;
                    rs += p;
                }
            rs += __shfl_xor(rs, 16);
            rs += __shfl_xor(rs, 32);
            li[nf] = li[nf] * alpha + rs;
            mi[nf] = mnew;
#pragma unroll
            for (int hf = 0; hf < 8; ++hf) {
                o[hf][nf][0] *= alpha; o[hf][nf][1] *= alpha;
                o[hf][nf][2] *= alpha; o[hf][nf][3] *= alpha;
            }
            // pack P (consecutive keys in-lane) -> b32 LDS writes
            int ql = nf * 16 + l16;
#pragma unroll
            for (int mf = 0; mf < 4; ++mf) {
                bf16x2 w0 = {(__bf16)s[mf][nf][0], (__bf16)s[mf][nf][1]};
                bf16x2 w1 = {(__bf16)s[mf][nf][2], (__bf16)s[mf][nf][3]};
                *(bf16x2*)&plT[wid][ql][mf * 16 + quad * 4]     = w0;
                *(bf16x2*)&plT[wid][ql][mf * 16 + quad * 4 + 2] = w1;
            }
        }
        asm volatile("s_waitcnt lgkmcnt(0)" ::: "memory"); // per-wave DS order
        // ---- O^T += V^T P^T (V frags straight from global) ----
        bf16x8 pb0[2], pb1[2];
#pragma unroll
        for (int nf = 0; nf < 2; ++nf) {
            pb0[nf] = *(const bf16x8*)&plT[wid][nf * 16 + l16][quad * 8];
            pb1[nf] = *(const bf16x8*)&plT[wid][nf * 16 + l16][32 + quad * 8];
        }
        bf16x8 va1[8];
#pragma unroll
        for (int hf = 0; hf < 8; ++hf)
            va1[hf] = *(const bf16x8*)&vb[(size_t)(hf * 16) * 4096 + k0 + 32];
        __builtin_amdgcn_s_setprio(1);
#pragma unroll
        for (int hf = 0; hf < 8; ++hf)
#pragma unroll
            for (int nf = 0; nf < 2; ++nf)
                o[hf][nf] = MFMA16(va0[hf], pb0[nf], o[hf][nf]);
#pragma unroll
        for (int hf = 0; hf < 8; ++hf)
#pragma unroll
            for (int nf = 0; nf < 2; ++nf)
                o[hf][nf] = MFMA16(va1[hf], pb1[nf], o[hf][nf]);
        __builtin_amdgcn_s_setprio(0);
    }

    // ---- epilogue: transpose O^T via LDS, coalesced bf16 partial store ----
    __syncthreads();                                   // plT dead; OL overlays
    float inv[2];
#pragma unroll
    for (int nf = 0; nf < 2; ++nf) inv[nf] = (li[nf] > 0.f) ? 1.0f / li[nf] : 0.f;
#pragma unroll
    for (int nf = 0; nf < 2; ++nf) {
        int ql = wid * 32 + nf * 16 + l16;
#pragma unroll
        for (int hf = 0; hf < 8; ++hf) {
            int hd = hf * 16 + quad * 4;
            bf16x2 w0 = {(__bf16)(o[hf][nf][0] * inv[nf]), (__bf16)(o[hf][nf][1] * inv[nf])};
            bf16x2 w1 = {(__bf16)(o[hf][nf][2] * inv[nf]), (__bf16)(o[hf][nf][3] * inv[nf])};
            *(bf16x2*)&OL[ql][hd]     = w0;
            *(bf16x2*)&OL[ql][hd + 2] = w1;
        }
        if (quad == 0) {
            size_t base = ((size_t)slot * 128 + ql) * 2;
            ml[base]     = mi[nf];
            ml[base + 1] = li[nf];
        }
    }
    __syncthreads();
    __bf16* dst = (j < 2)
        ? (__bf16*)((char*)out + (sb + r0) * 512 + (size_t)j * 32768)
        : pex + ((size_t)(b * NPEX + cumex + (j - 2))) * 16384;
    {
        int qrow = tid >> 1, cb2 = (tid & 1) * 64;
#pragma unroll
        for (int i = 0; i < 8; ++i) {
            bf16x8 v = *(const bf16x8*)&OL[qrow][cb2 + i * 8];
            *(bf16x8*)&dst[(size_t)qrow * 128 + cb2 + i * 8] = v;
        }
    }
}

// ----------------------------------------------------------------- mergeN ---
// v11: (256,2) -> no RA clamp (needs ~150 VGPR: acc[64] + rg0/rg1 + temps;
// the default heuristic was almost certainly spilling this one too).
__global__ __launch_bounds__(256, 2) void mergeN(
    float* __restrict__ out, const float* __restrict__ ml,
    const __bf16* __restrict__ pex, int C, int NS, int NPEX)
{
    const int T = blockIdx.x, b = blockIdx.y;
    int cum = 0, cumex = 0;
    for (int tt = 0; tt < T; ++tt) {
        int nn = (2 * (tt + 1) + C - 1) / C;
        cum += nn;
        cumex += (nn > 2) ? (nn - 2) : 0;
    }
    const int n  = (2 * (T + 1) + C - 1) / C;
    const int r0 = T * 128;
    const size_t sb = (size_t)b * 4096;
    const int ql = threadIdx.x >> 1, ch = (threadIdx.x & 1) * 64;
    const int slot0 = b * NS + cum;

    float mm = -1e30f;
    for (int jj = 0; jj < n; ++jj)
        mm = fmaxf(mm, ml[((size_t)(slot0 + jj) * 128 + ql) * 2]);

    // stage the (up to 2) in-out partials before overwriting out
    const __bf16* pout = (const __bf16*)((const char*)out + (sb + r0) * 512);
    bf16x8 rg0[8], rg1[8];
#pragma unroll
    for (int q2 = 0; q2 < 8; ++q2)
        rg0[q2] = *(const bf16x8*)&pout[(size_t)ql * 128 + ch + q2 * 8];
#pragma unroll
    for (int q2 = 0; q2 < 8; ++q2)
        rg1[q2] = *(const bf16x8*)&pout[16384 + (size_t)ql * 128 + ch + q2 * 8];
    __syncthreads();                                   // all reads done

    float acc[64];
#pragma unroll
    for (int k = 0; k < 64; ++k) acc[k] = 0.f;
    float den = 0.f;
    {   // j = 0 (always exists)
        size_t base = ((size_t)slot0 * 128 + ql) * 2;
        float m = ml[base], l = ml[base + 1];
        float w = (l > 0.f) ? EXP2F(m - mm) * l : 0.f;
        den += w;
#pragma unroll
        for (int q2 = 0; q2 < 8; ++q2)
#pragma unroll
            for (int e = 0; e < 8; ++e)
                acc[q2 * 8 + e] += w * (float)rg0[q2][e];
    }
    if (n > 1) {   // j = 1
        size_t base = ((size_t)(slot0 + 1) * 128 + ql) * 2;
        float m = ml[base], l = ml[base + 1];
        float w = (l > 0.f) ? EXP2F(m - mm) * l : 0.f;
        den += w;
#pragma unroll
        for (int q2 = 0; q2 < 8; ++q2)
#pragma unroll
            for (int e = 0; e < 8; ++e)
                acc[q2 * 8 + e] += w * (float)rg1[q2][e];
    }
    for (int jj = 2; jj < n; ++jj) {
        size_t base = ((size_t)(slot0 + jj) * 128 + ql) * 2;
        float m = ml[base], l = ml[base + 1];
        float w = (l > 0.f) ? EXP2F(m - mm) * l : 0.f;
        den += w;
        const __bf16* p = pex + ((size_t)(b * NPEX + cumex + (jj - 2))) * 16384
                        + (size_t)ql * 128 + ch;
#pragma unroll
        for (int q2 = 0; q2 < 8; ++q2) {
            bf16x8 v = *(const bf16x8*)&p[q2 * 8];
#pragma unroll
            for (int e = 0; e < 8; ++e)
                acc[q2 * 8 + e] += w * (float)v[e];
        }
    }
    float sc = (den > 0.f) ? 1.0f / den : 0.f;
    float* op = &out[(sb + r0 + ql) * 128 + ch];
#pragma unroll
    for (int q2 = 0; q2 < 8; ++q2) {
        float4 v0 = {acc[q2 * 8 + 0] * sc, acc[q2 * 8 + 1] * sc,
                     acc[q2 * 8 + 2] * sc, acc[q2 * 8 + 3] * sc};
        float4 v1 = {acc[q2 * 8 + 4] * sc, acc[q2 * 8 + 5] * sc,
                     acc[q2 * 8 + 6] * sc, acc[q2 * 8 + 7] * sc};
        *(float4*)&op[q2 * 8]     = v0;
        *(float4*)&op[q2 * 8 + 4] = v1;
    }
}

// ----------------------------------------------------------------- launch ---
extern "C" void kernel_launch(void* const* d_in, const int* in_sizes, int n_in,
                              void* d_out, int out_size, void* d_ws, size_t ws_size,
                              hipStream_t stream)
{
    const float* x    = (const float*)d_in[0];
    const int*   mask = (const int*)d_in[1];
    const float* Wq   = (const float*)d_in[2];
    const float* bq   = (const float*)d_in[3];
    const float* Wk   = (const float*)d_in[4];
    const float* bk   = (const float*)d_in[5];
    const float* Wv   = (const float*)d_in[6];
    const float* bv   = (const float*)d_in[7];
    float* out = (float*)d_out;

    char* ws = (char*)d_ws;
    __bf16* Qb  = (__bf16*)ws;                        // 4 MiB
    __bf16* Kb  = Qb + (size_t)16384 * 128;           // 4 MiB
    __bf16* Vt  = Kb + (size_t)16384 * 128;           // 4 MiB ([b][h][s])
    __bf16* Wb  = Vt + (size_t)16384 * 128;           // 768 KiB @ 12,582,912
    const size_t PEX_OFF = 13369344;

    // --- tier the chunk size by workspace capacity ---
    const int Cs[3] = {5, 6, 10};
    int C = 10, NS = 0, NPEX = 0;
    size_t mlOff = 0;
    for (int ci = 0; ci < 3; ++ci) {
        int c = Cs[ci], ns = 0, npex = 0;
        for (int T = 0; T < 32; ++T) {
            int n = (2 * (T + 1) + c - 1) / c;
            ns += n;
            npex += (n > 2) ? (n - 2) : 0;
        }
        size_t mlBytes  = (size_t)4 * ns * 1024;      // 4b x ns slots x 128q x 2 f32
        size_t pexBytes = (size_t)4 * npex * 32768;   // 4b x npex tiles x 128x128 bf16
        size_t mlo, tot;
        if (mlBytes <= 786432) { mlo = 12582912; tot = PEX_OFF + pexBytes; }
        else                   { mlo = PEX_OFF + pexBytes; tot = mlo + mlBytes; }
        if (tot <= ws_size || ci == 2) {
            C = c; NS = ns; NPEX = npex; mlOff = mlo;
            break;
        }
    }
    float*  ml  = (float*)(ws + mlOff);
    __bf16* pex = (__bf16*)(ws + PEX_OFF);

    prep_w<<<384, 256, 0, stream>>>(Wq, Wk, Wv, Wb);
    qkv_gemm<<<768, 256, 0, stream>>>(x, Wb, bq, bk, bv, Qb, Kb, Vt);
    flash_attn<<<4 * NS, 256, 0, stream>>>(Qb, Kb, Vt, mask, out, ml, pex, C, NS, NPEX);
    mergeN<<<dim3(32, 4), 256, 0, stream>>>(out, ml, pex, C, NS, NPEX);
}

// Round 5
// 257.501 us; speedup vs baseline: 1.4726x; 1.1447x over previous
//
#include <hip/hip_runtime.h>

// MaskedSelfAttention: B=4, S=4096, D=1024, H=128. fp32 in/out, bf16 MFMA compute.
// v12: qkv_gemm rebuilt on global_load_lds (m97 pattern). v11 post-mortem:
// VGPR=68 under default/(256,2)/(256,3) alike, WRITE 124-167MB vs 13MB legit
// -> the 32 long-lived staging regs spill no matter the bounds; codegen (not
// traffic) explains v9's 184 vs v11's 91. Fix: zero-staging-reg DMA staging.
//  - A (x, fp32): global_load_lds 16B/lane into As[2][64][64] f32 (convert to
//    bf16 at fragment read). B (Wb): into Bs[2][128][64] bf16.
//  - Swizzle BOTH sides (rule #21): source chunk pre-XOR (c ^ (row&7)), linear
//    LDS dest (gload_lds requirement), XOR'd read addr -> 2-way (free) banks.
//  - LDS 64KB -> 2 blocks/CU (= v8 residency). XCD slab grouping kept
//    (FETCH 40.7MB verified v9/v11).
// flash_attn / mergeN / prep_w unchanged from v11.

typedef __bf16 bf16x8 __attribute__((ext_vector_type(8)));
typedef __bf16 bf16x4 __attribute__((ext_vector_type(4)));
typedef __bf16 bf16x2 __attribute__((ext_vector_type(2)));
typedef float  f32x4  __attribute__((ext_vector_type(4)));

#define MFMA16(a, b, c) __builtin_amdgcn_mfma_f32_16x16x32_bf16(a, b, c, 0, 0, 0)
#define EXP2F(x) __builtin_amdgcn_exp2f(x)

__device__ __forceinline__ void gld_lds16(const void* g, void* l)
{
    __builtin_amdgcn_global_load_lds(
        (const __attribute__((address_space(1))) void*)g,
        (__attribute__((address_space(3))) void*)l, 16, 0, 0);
}

// ---------------------------------------------------------------- prep_w ----
__global__ __launch_bounds__(256) void prep_w(
    const float* __restrict__ Wq, const float* __restrict__ Wk,
    const float* __restrict__ Wv, __bf16* __restrict__ Wb)
{
    int i = (blockIdx.x * 256 + threadIdx.x) * 4;
    int row = i >> 10;
    const float* W = (row < 128) ? Wq : (row < 256) ? Wk : Wv;
    float4 v = *(const float4*)&W[(size_t)(row & 127) * 1024 + (i & 1023)];
    bf16x4 pk = {(__bf16)v.x, (__bf16)v.y, (__bf16)v.z, (__bf16)v.w};
    *(bf16x4*)&Wb[i] = pk;
}

// -------------------------------------------------------------- qkv_gemm ----
// v12: 64x128 tile, BK=64, 4 waves 2x2. Staging is pure global_load_lds
// (8 insts/wave/iter, 16B/lane): A rows 256B = 16 lanes, B rows 128B = 8
// lanes. Logical chunk c of row r lives at phys chunk c^(r&7) (source
// pre-swizzled, read XOR'd) -> fragment reads are 2-way bank-aliased (free).
// One barrier per iter (syncthreads drains the in-flight DMA of tile t+1
// after tile t's MFMA - m97 structure).
__global__ __launch_bounds__(256, 2) void qkv_gemm(
    const float* __restrict__ x, const __bf16* __restrict__ Wb,
    const float* __restrict__ bq, const float* __restrict__ bk,
    const float* __restrict__ bv,
    __bf16* __restrict__ Qb, __bf16* __restrict__ Kb, __bf16* __restrict__ Vt)
{
    __shared__ __align__(16) float  As[2][64][64];    // 32 KiB
    __shared__ __align__(16) __bf16 Bs[2][128][64];   // 32 KiB

    const int tid   = threadIdx.x;
    const int bx    = blockIdx.x;
    const int xcd   = bx & 7, w8 = bx >> 3;   // 96 blocks per xcd
    const int slab  = xcd * 32 + w8 / 3;      // 0..255
    const int which = w8 % 3;                 // 0=Q 1=K 2=V
    const int m0    = slab * 64;
    const int n0    = which * 128;
    const int lane = tid & 63, wid = tid >> 6;
    const int quad = lane >> 4, l16 = lane & 15;
    const int wm = (wid >> 1) * 32, wn = (wid & 1) * 64;

    const f32x4 fzero = {0.f, 0.f, 0.f, 0.f};
    f32x4 acc[2][4];
#pragma unroll
    for (int i = 0; i < 2; ++i)
#pragma unroll
        for (int j = 0; j < 4; ++j) acc[i][j] = fzero;

    // staging decomposition (per wave: 4 A-insts + 4 B-insts, 1KiB each)
    const int rlA = lane >> 4, cA = lane & 15;        // A: 4 rows/inst
    const int rlB = lane >> 3, cB = lane & 7;         // B: 8 rows/inst

#define STAGE(bufi, kk)                                                        \
    {                                                                          \
        _Pragma("unroll")                                                      \
        for (int i = 0; i < 4; ++i) {                                          \
            int R  = wid * 16 + i * 4;                                         \
            int sw = (i & 1) * 4 + rlA;              /* (R+rlA)&7 */           \
            gld_lds16(&x[(size_t)(m0 + R + rlA) * 1024 + (kk) + ((cA ^ sw) * 4)],\
                      &As[bufi][R][0]);                                        \
        }                                                                      \
        _Pragma("unroll")                                                      \
        for (int i = 0; i < 4; ++i) {                                          \
            int R = wid * 32 + i * 8;                                          \
            gld_lds16(&Wb[(size_t)(n0 + R + rlB) * 1024 + (kk) + ((cB ^ rlB) * 8)],\
                      &Bs[bufi][R][0]);                                        \
        }                                                                      \
    }

    STAGE(0, 0);
    __syncthreads();

    const int sA = l16 & 7;
    for (int t = 0; t < 16; ++t) {
        const int buf = t & 1;
        if (t < 15) STAGE(buf ^ 1, (t + 1) * 64);     // DMA flies under MFMA
#pragma unroll
        for (int ks = 0; ks < 2; ++ks) {
            bf16x8 a[2], bb[4];
#pragma unroll
            for (int mt = 0; mt < 2; ++mt) {
                int r  = wm + mt * 16 + l16;
                int c0 = ks * 8 + quad * 2;
                f32x4 a0 = *(const f32x4*)&As[buf][r][(c0 ^ sA) * 4];
                f32x4 a1 = *(const f32x4*)&As[buf][r][((c0 + 1) ^ sA) * 4];
                a[mt] = (bf16x8){(__bf16)a0[0], (__bf16)a0[1], (__bf16)a0[2], (__bf16)a0[3],
                                 (__bf16)a1[0], (__bf16)a1[1], (__bf16)a1[2], (__bf16)a1[3]};
            }
#pragma unroll
            for (int nt = 0; nt < 4; ++nt) {
                int r  = wn + nt * 16 + l16;
                int cc = (ks * 4 + quad) ^ sA;
                bb[nt] = *(const bf16x8*)&Bs[buf][r][cc * 8];
            }
#pragma unroll
            for (int mt = 0; mt < 2; ++mt)
#pragma unroll
                for (int nt = 0; nt < 4; ++nt)
                    acc[mt][nt] = MFMA16(a[mt], bb[nt], acc[mt][nt]);
        }
        __syncthreads();   // drains tile t+1's DMA (vmcnt 0) + barrier
    }

    const float* bias = (which == 0) ? bq : (which == 1) ? bk : bv;
    if (which < 2) {
        __bf16* dst = (which == 0) ? Qb : Kb;
#pragma unroll
        for (int nt = 0; nt < 4; ++nt) {
            int col = wn + nt * 16 + l16;
            float bvv = bias[col];
#pragma unroll
            for (int mt = 0; mt < 2; ++mt)
#pragma unroll
                for (int r = 0; r < 4; ++r) {
                    int row = m0 + wm + mt * 16 + quad * 4 + r;
                    dst[(size_t)row * 128 + col] = (__bf16)(acc[mt][nt][r] + bvv);
                }
        }
    } else {
#pragma unroll
        for (int nt = 0; nt < 4; ++nt) {
            int col = wn + nt * 16 + l16;               // head index
            float bvv = bias[col];
#pragma unroll
            for (int mt = 0; mt < 2; ++mt) {
                int row = m0 + wm + mt * 16 + quad * 4;
                int bb_ = row >> 12, s = row & 4095;
                bf16x4 pk = {(__bf16)(acc[mt][nt][0] + bvv),
                             (__bf16)(acc[mt][nt][1] + bvv),
                             (__bf16)(acc[mt][nt][2] + bvv),
                             (__bf16)(acc[mt][nt][3] + bvv)};
                *(bf16x4*)&Vt[((size_t)(bb_ * 128 + col)) * 4096 + s] = pk;
            }
        }
    }
#undef STAGE
}

// -------------------------------------------------------------- flash_attn --
// unchanged from v11: barrier-free main loop, K/V frags direct from global
// (fragment layout == memory layout), plT-only LDS, runtime chunk C,
// setprio around MFMA clusters. (256,2): VGPR 124, 4 blocks/CU by resources.
__global__ __launch_bounds__(256, 2) void flash_attn(
    const __bf16* __restrict__ Qb, const __bf16* __restrict__ Kb,
    const __bf16* __restrict__ Vt, const int* __restrict__ mask,
    float* __restrict__ out, float* __restrict__ ml, __bf16* __restrict__ pex,
    int C, int NS, int NPEX)
{
    __shared__ __align__(16) char smem[34816];
    __bf16 (*plT)[32][72] = (__bf16(*)[32][72])smem;   // [wave][q32][key64+pad]
    __bf16 (*OL)[136]     = (__bf16(*)[136])smem;      // epilogue overlay

    // ---- block -> (T, b, j): n(T)=ceil(2(T+1)/C) chunks of <=C key-iters ----
    int ii = blockIdx.x, T = 0, n, cum = 0, cumex = 0;
    for (;; ++T) {
        n = (2 * (T + 1) + C - 1) / C;
        if (ii < 4 * n) break;
        ii -= 4 * n;
        cum += n;                            // per-b slot prefix
        cumex += (n > 2) ? (n - 2) : 0;      // per-b pex prefix
    }
    const int b  = ii / n;
    const int j  = ii % n;
    const int nk = 2 * (T + 1);
    const int t0 = j * C;
    const int t1 = (nk < t0 + C) ? nk : (t0 + C);
    const int r0 = T * 128;
    const int slot = b * NS + cum + j;       // ml slot id

    const int tid = threadIdx.x, wid = tid >> 6, lane = tid & 63;
    const int quad = lane >> 4, l16 = lane & 15;
    const int qw = r0 + wid * 32;                      // wave's q base
    const size_t sb = (size_t)b * 4096;
    const float qs = 0.08838834764831845f * 1.4426950408889634f; // scale*log2e

    bf16x8 qf[2][4];                                   // Q B-frags, scale folded
#pragma unroll
    for (int nf = 0; nf < 2; ++nf)
#pragma unroll
        for (int ks = 0; ks < 4; ++ks) {
            qf[nf][ks] = *(const bf16x8*)
                &Qb[(sb + qw + nf * 16 + l16) * 128 + ks * 32 + quad * 8];
#pragma unroll
            for (int e = 0; e < 8; ++e)
                qf[nf][ks][e] = (__bf16)((float)qf[nf][ks][e] * qs);
        }

    float mi[2] = {-1e30f, -1e30f}, li[2] = {0.f, 0.f};
    const f32x4 fzero = {0.f, 0.f, 0.f, 0.f};
    f32x4 o[8][2];                                     // O^T: 8 head-frags x 2 q-frags
#pragma unroll
    for (int hf = 0; hf < 8; ++hf)
#pragma unroll
        for (int nf = 0; nf < 2; ++nf) o[hf][nf] = fzero;

    // per-lane fragment base pointers (global = fragment layout)
    const __bf16* kb = Kb + (sb + l16) * 128 + quad * 8;
    const __bf16* vb = Vt + ((size_t)b * 128 + l16) * 4096 + quad * 8;

    for (int t = t0; t < t1; ++t) {
        const int k0 = t * 64;
        const int mv = mask[sb + k0 + lane];

        // ---- S^T = K Q^T: rows=keys(64, 4 mf), cols=q(32, 2 nf) ----
        f32x4 s[4][2];
#pragma unroll
        for (int mf = 0; mf < 4; ++mf)
#pragma unroll
            for (int nf = 0; nf < 2; ++nf) s[mf][nf] = fzero;
        __builtin_amdgcn_s_setprio(1);
#pragma unroll
        for (int ks = 0; ks < 4; ++ks) {
            bf16x8 a[4];
#pragma unroll
            for (int mf = 0; mf < 4; ++mf)
                a[mf] = *(const bf16x8*)&kb[(size_t)(k0 + mf * 16) * 128 + ks * 32];
#pragma unroll
            for (int mf = 0; mf < 4; ++mf)
#pragma unroll
                for (int nf = 0; nf < 2; ++nf)
                    s[mf][nf] = MFMA16(a[mf], qf[nf][ks], s[mf][nf]);
        }
        __builtin_amdgcn_s_setprio(0);
        // prefetch PV first half's V frags above the softmax (hides L2 latency)
        bf16x8 va0[8];
#pragma unroll
        for (int hf = 0; hf < 8; ++hf)
            va0[hf] = *(const bf16x8*)&vb[(size_t)(hf * 16) * 4096 + k0];

        // ---- masking (C-layout: key = mf*16+quad*4+r, q = qw+nf*16+l16) ----
        unsigned long long mb = __ballot(mv != 0);
        if (mb != ~0ull || k0 + 63 > qw) {
#pragma unroll
            for (int mf = 0; mf < 4; ++mf)
#pragma unroll
                for (int r = 0; r < 4; ++r) {
                    int kl = mf * 16 + quad * 4 + r;
                    bool mok = (mb >> kl) & 1;
                    int kc = k0 + kl;
#pragma unroll
                    for (int nf = 0; nf < 2; ++nf) {
                        int q = qw + nf * 16 + l16;
                        bool ok = mok && (kc <= q);
                        s[mf][nf][r] = ok ? s[mf][nf][r] : -1e30f;
                    }
                }
        }
        // ---- online softmax per q (log2 domain; reduce over quads) ----
#pragma unroll
        for (int nf = 0; nf < 2; ++nf) {
            float mx = s[0][nf][0];
#pragma unroll
            for (int mf = 0; mf < 4; ++mf)
#pragma unroll
                for (int r = 0; r < 4; ++r) mx = fmaxf(mx, s[mf][nf][r]);
            mx = fmaxf(mx, __shfl_xor(mx, 16));
            mx = fmaxf(mx, __shfl_xor(mx, 32));
            float mnew  = fmaxf(mi[nf], mx);
            float alpha = EXP2F(mi[nf] - mnew);
            float rs = 0.f;
#pragma unroll
            for (int mf = 0; mf < 4; ++mf)
#pragma unroll
                for (int r = 0; r < 4; ++r) {
                    float sv = s[mf][nf][r];
                    float p = (sv < -5e29f) ? 0.f : EXP2F(sv - mnew);
                    s[mf][nf][r] = p;
                    rs += p;
                }
            rs += __shfl_xor(rs, 16);
            rs += __shfl_xor(rs, 32);
            li[nf] = li[nf] * alpha + rs;
            mi[nf] = mnew;
#pragma unroll
            for (int hf = 0; hf < 8; ++hf) {
                o[hf][nf][0] *= alpha; o[hf][nf][1] *= alpha;
                o[hf][nf][2] *= alpha; o[hf][nf][3] *= alpha;
            }
            // pack P (consecutive keys in-lane) -> b32 LDS writes
            int ql = nf * 16 + l16;
#pragma unroll
            for (int mf = 0; mf < 4; ++mf) {
                bf16x2 w0 = {(__bf16)s[mf][nf][0], (__bf16)s[mf][nf][1]};
                bf16x2 w1 = {(__bf16)s[mf][nf][2], (__bf16)s[mf][nf][3]};
                *(bf16x2*)&plT[wid][ql][mf * 16 + quad * 4]     = w0;
                *(bf16x2*)&plT[wid][ql][mf * 16 + quad * 4 + 2] = w1;
            }
        }
        asm volatile("s_waitcnt lgkmcnt(0)" ::: "memory"); // per-wave DS order
        // ---- O^T += V^T P^T (V frags straight from global) ----
        bf16x8 pb0[2], pb1[2];
#pragma unroll
        for (int nf = 0; nf < 2; ++nf) {
            pb0[nf] = *(const bf16x8*)&plT[wid][nf * 16 + l16][quad * 8];
            pb1[nf] = *(const bf16x8*)&plT[wid][nf * 16 + l16][32 + quad * 8];
        }
        bf16x8 va1[8];
#pragma unroll
        for (int hf = 0; hf < 8; ++hf)
            va1[hf] = *(const bf16x8*)&vb[(size_t)(hf * 16) * 4096 + k0 + 32];
        __builtin_amdgcn_s_setprio(1);
#pragma unroll
        for (int hf = 0; hf < 8; ++hf)
#pragma unroll
            for (int nf = 0; nf < 2; ++nf)
                o[hf][nf] = MFMA16(va0[hf], pb0[nf], o[hf][nf]);
#pragma unroll
        for (int hf = 0; hf < 8; ++hf)
#pragma unroll
            for (int nf = 0; nf < 2; ++nf)
                o[hf][nf] = MFMA16(va1[hf], pb1[nf], o[hf][nf]);
        __builtin_amdgcn_s_setprio(0);
    }

    // ---- epilogue: transpose O^T via LDS, coalesced bf16 partial store ----
    __syncthreads();                                   // plT dead; OL overlays
    float inv[2];
#pragma unroll
    for (int nf = 0; nf < 2; ++nf) inv[nf] = (li[nf] > 0.f) ? 1.0f / li[nf] : 0.f;
#pragma unroll
    for (int nf = 0; nf < 2; ++nf) {
        int ql = wid * 32 + nf * 16 + l16;
#pragma unroll
        for (int hf = 0; hf < 8; ++hf) {
            int hd = hf * 16 + quad * 4;
            bf16x2 w0 = {(__bf16)(o[hf][nf][0] * inv[nf]), (__bf16)(o[hf][nf][1] * inv[nf])};
            bf16x2 w1 = {(__bf16)(o[hf][nf][2] * inv[nf]), (__bf16)(o[hf][nf][3] * inv[nf])};
            *(bf16x2*)&OL[ql][hd]     = w0;
            *(bf16x2*)&OL[ql][hd + 2] = w1;
        }
        if (quad == 0) {
            size_t base = ((size_t)slot * 128 + ql) * 2;
            ml[base]     = mi[nf];
            ml[base + 1] = li[nf];
        }
    }
    __syncthreads();
    __bf16* dst = (j < 2)
        ? (__bf16*)((char*)out + (sb + r0) * 512 + (size_t)j * 32768)
        : pex + ((size_t)(b * NPEX + cumex + (j - 2))) * 16384;
    {
        int qrow = tid >> 1, cb2 = (tid & 1) * 64;
#pragma unroll
        for (int i = 0; i < 8; ++i) {
            bf16x8 v = *(const bf16x8*)&OL[qrow][cb2 + i * 8];
            *(bf16x8*)&dst[(size_t)qrow * 128 + cb2 + i * 8] = v;
        }
    }
}

// ----------------------------------------------------------------- mergeN ---
// One block per (b,T): combine n(T) pre-normalized bf16 partials (j<2 from
// the tile's own out rows, staged to regs before overwrite; j>=2 streamed from
// pex) into final fp32. (256,2): no RA clamp.
__global__ __launch_bounds__(256, 2) void mergeN(
    float* __restrict__ out, const float* __restrict__ ml,
    const __bf16* __restrict__ pex, int C, int NS, int NPEX)
{
    const int T = blockIdx.x, b = blockIdx.y;
    int cum = 0, cumex = 0;
    for (int tt = 0; tt < T; ++tt) {
        int nn = (2 * (tt + 1) + C - 1) / C;
        cum += nn;
        cumex += (nn > 2) ? (nn - 2) : 0;
    }
    const int n  = (2 * (T + 1) + C - 1) / C;
    const int r0 = T * 128;
    const size_t sb = (size_t)b * 4096;
    const int ql = threadIdx.x >> 1, ch = (threadIdx.x & 1) * 64;
    const int slot0 = b * NS + cum;

    float mm = -1e30f;
    for (int jj = 0; jj < n; ++jj)
        mm = fmaxf(mm, ml[((size_t)(slot0 + jj) * 128 + ql) * 2]);

    // stage the (up to 2) in-out partials before overwriting out
    const __bf16* pout = (const __bf16*)((const char*)out + (sb + r0) * 512);
    bf16x8 rg0[8], rg1[8];
#pragma unroll
    for (int q2 = 0; q2 < 8; ++q2)
        rg0[q2] = *(const bf16x8*)&pout[(size_t)ql * 128 + ch + q2 * 8];
#pragma unroll
    for (int q2 = 0; q2 < 8; ++q2)
        rg1[q2] = *(const bf16x8*)&pout[16384 + (size_t)ql * 128 + ch + q2 * 8];
    __syncthreads();                                   // all reads done

    float acc[64];
#pragma unroll
    for (int k = 0; k < 64; ++k) acc[k] = 0.f;
    float den = 0.f;
    {   // j = 0 (always exists)
        size_t base = ((size_t)slot0 * 128 + ql) * 2;
        float m = ml[base], l = ml[base + 1];
        float w = (l > 0.f) ? EXP2F(m - mm) * l : 0.f;
        den += w;
#pragma unroll
        for (int q2 = 0; q2 < 8; ++q2)
#pragma unroll
            for (int e = 0; e < 8; ++e)
                acc[q2 * 8 + e] += w * (float)rg0[q2][e];
    }
    if (n > 1) {   // j = 1
        size_t base = ((size_t)(slot0 + 1) * 128 + ql) * 2;
        float m = ml[base], l = ml[base + 1];
        float w = (l > 0.f) ? EXP2F(m - mm) * l : 0.f;
        den += w;
#pragma unroll
        for (int q2 = 0; q2 < 8; ++q2)
#pragma unroll
            for (int e = 0; e < 8; ++e)
                acc[q2 * 8 + e] += w * (float)rg1[q2][e];
    }
    for (int jj = 2; jj < n; ++jj) {
        size_t base = ((size_t)(slot0 + jj) * 128 + ql) * 2;
        float m = ml[base], l = ml[base + 1];
        float w = (l > 0.f) ? EXP2F(m - mm) * l : 0.f;
        den += w;
        const __bf16* p = pex + ((size_t)(b * NPEX + cumex + (jj - 2))) * 16384
                        + (size_t)ql * 128 + ch;
#pragma unroll
        for (int q2 = 0; q2 < 8; ++q2) {
            bf16x8 v = *(const bf16x8*)&p[q2 * 8];
#pragma unroll
            for (int e = 0; e < 8; ++e)
                acc[q2 * 8 + e] += w * (float)v[e];
        }
    }
    float sc = (den > 0.f) ? 1.0f / den : 0.f;
    float* op = &out[(sb + r0 + ql) * 128 + ch];
#pragma unroll
    for (int q2 = 0; q2 < 8; ++q2) {
        float4 v0 = {acc[q2 * 8 + 0] * sc, acc[q2 * 8 + 1] * sc,
                     acc[q2 * 8 + 2] * sc, acc[q2 * 8 + 3] * sc};
        float4 v1 = {acc[q2 * 8 + 4] * sc, acc[q2 * 8 + 5] * sc,
                     acc[q2 * 8 + 6] * sc, acc[q2 * 8 + 7] * sc};
        *(float4*)&op[q2 * 8]     = v0;
        *(float4*)&op[q2 * 8 + 4] = v1;
    }
}

// ----------------------------------------------------------------- launch ---
extern "C" void kernel_launch(void* const* d_in, const int* in_sizes, int n_in,
                              void* d_out, int out_size, void* d_ws, size_t ws_size,
                              hipStream_t stream)
{
    const float* x    = (const float*)d_in[0];
    const int*   mask = (const int*)d_in[1];
    const float* Wq   = (const float*)d_in[2];
    const float* bq   = (const float*)d_in[3];
    const float* Wk   = (const float*)d_in[4];
    const float* bk   = (const float*)d_in[5];
    const float* Wv   = (const float*)d_in[6];
    const float* bv   = (const float*)d_in[7];
    float* out = (float*)d_out;

    char* ws = (char*)d_ws;
    __bf16* Qb  = (__bf16*)ws;                        // 4 MiB
    __bf16* Kb  = Qb + (size_t)16384 * 128;           // 4 MiB
    __bf16* Vt  = Kb + (size_t)16384 * 128;           // 4 MiB ([b][h][s])
    __bf16* Wb  = Vt + (size_t)16384 * 128;           // 768 KiB @ 12,582,912
    const size_t PEX_OFF = 13369344;

    // --- tier the chunk size by workspace capacity ---
    const int Cs[3] = {5, 6, 10};
    int C = 10, NS = 0, NPEX = 0;
    size_t mlOff = 0;
    for (int ci = 0; ci < 3; ++ci) {
        int c = Cs[ci], ns = 0, npex = 0;
        for (int T = 0; T < 32; ++T) {
            int n = (2 * (T + 1) + c - 1) / c;
            ns += n;
            npex += (n > 2) ? (n - 2) : 0;
        }
        size_t mlBytes  = (size_t)4 * ns * 1024;      // 4b x ns slots x 128q x 2 f32
        size_t pexBytes = (size_t)4 * npex * 32768;   // 4b x npex tiles x 128x128 bf16
        size_t mlo, tot;
        if (mlBytes <= 786432) { mlo = 12582912; tot = PEX_OFF + pexBytes; }
        else                   { mlo = PEX_OFF + pexBytes; tot = mlo + mlBytes; }
        if (tot <= ws_size || ci == 2) {
            C = c; NS = ns; NPEX = npex; mlOff = mlo;
            break;
        }
    }
    float*  ml  = (float*)(ws + mlOff);
    __bf16* pex = (__bf16*)(ws + PEX_OFF);

    prep_w<<<384, 256, 0, stream>>>(Wq, Wk, Wv, Wb);
    qkv_gemm<<<768, 256, 0, stream>>>(x, Wb, bq, bk, bv, Qb, Kb, Vt);
    flash_attn<<<4 * NS, 256, 0, stream>>>(Qb, Kb, Vt, mask, out, ml, pex, C, NS, NPEX);
    mergeN<<<dim3(32, 4), 256, 0, stream>>>(out, ml, pex, C, NS, NPEX);
}

// Round 6
// 205.365 us; speedup vs baseline: 1.8465x; 1.2539x over previous
//
#include <hip/hip_runtime.h>

// MaskedSelfAttention: B=4, S=4096, D=1024, H=128. fp32 in/out, bf16 MFMA compute.
// v13: flash stages K through LDS via global_load_lds (the v12 qkv recipe that
// removed qkv from the top-5): double-buffered Ks[2][64][128], XOR-swizzled
// both-sides (src chunk c^(row&7), linear LDS dst, XOR'd ds_read), one barrier
// per iter. Removes the 16 exposed L2-latency K loads per wave-iter (80%
// memory-stall at VALUBusy 12.6/MfmaUtil 7.1) and the 4x per-block K
// duplication. V stays direct+prefetch (LDS 50KB -> 3 blocks/CU). Grid back
// to C=10/476 blocks (896 measured slower: occupancy grid-invariant ~16.6%,
// extra blocks only add Q-refetch: FETCH 23.8->41MB). mergeN: 4-way z-split
// (512 blocks, was 128 at ~0.5/CU); all partials now in pex (no out-aliasing
// -> no cross-block hazard, no stage+barrier). ws 27.6MiB (v9 proved fit).
// qkv_gemm/prep_w unchanged from v12.

typedef __bf16 bf16x8 __attribute__((ext_vector_type(8)));
typedef __bf16 bf16x4 __attribute__((ext_vector_type(4)));
typedef __bf16 bf16x2 __attribute__((ext_vector_type(2)));
typedef float  f32x4  __attribute__((ext_vector_type(4)));

#define MFMA16(a, b, c) __builtin_amdgcn_mfma_f32_16x16x32_bf16(a, b, c, 0, 0, 0)
#define EXP2F(x) __builtin_amdgcn_exp2f(x)

__device__ __forceinline__ void gld_lds16(const void* g, void* l)
{
    __builtin_amdgcn_global_load_lds(
        (const __attribute__((address_space(1))) void*)g,
        (__attribute__((address_space(3))) void*)l, 16, 0, 0);
}

// ---------------------------------------------------------------- prep_w ----
__global__ __launch_bounds__(256) void prep_w(
    const float* __restrict__ Wq, const float* __restrict__ Wk,
    const float* __restrict__ Wv, __bf16* __restrict__ Wb)
{
    int i = (blockIdx.x * 256 + threadIdx.x) * 4;
    int row = i >> 10;
    const float* W = (row < 128) ? Wq : (row < 256) ? Wk : Wv;
    float4 v = *(const float4*)&W[(size_t)(row & 127) * 1024 + (i & 1023)];
    bf16x4 pk = {(__bf16)v.x, (__bf16)v.y, (__bf16)v.z, (__bf16)v.w};
    *(bf16x4*)&Wb[i] = pk;
}

// -------------------------------------------------------------- qkv_gemm ----
// v12 (verified fast): 64x128 tile, BK=64, staging via global_load_lds only,
// both-sides XOR swizzle, one barrier per iter, XCD slab grouping.
__global__ __launch_bounds__(256, 2) void qkv_gemm(
    const float* __restrict__ x, const __bf16* __restrict__ Wb,
    const float* __restrict__ bq, const float* __restrict__ bk,
    const float* __restrict__ bv,
    __bf16* __restrict__ Qb, __bf16* __restrict__ Kb, __bf16* __restrict__ Vt)
{
    __shared__ __align__(16) float  As[2][64][64];    // 32 KiB
    __shared__ __align__(16) __bf16 Bs[2][128][64];   // 32 KiB

    const int tid   = threadIdx.x;
    const int bx    = blockIdx.x;
    const int xcd   = bx & 7, w8 = bx >> 3;   // 96 blocks per xcd
    const int slab  = xcd * 32 + w8 / 3;      // 0..255
    const int which = w8 % 3;                 // 0=Q 1=K 2=V
    const int m0    = slab * 64;
    const int n0    = which * 128;
    const int lane = tid & 63, wid = tid >> 6;
    const int quad = lane >> 4, l16 = lane & 15;
    const int wm = (wid >> 1) * 32, wn = (wid & 1) * 64;

    const f32x4 fzero = {0.f, 0.f, 0.f, 0.f};
    f32x4 acc[2][4];
#pragma unroll
    for (int i = 0; i < 2; ++i)
#pragma unroll
        for (int j = 0; j < 4; ++j) acc[i][j] = fzero;

    const int rlA = lane >> 4, cA = lane & 15;        // A: 4 rows/inst
    const int rlB = lane >> 3, cB = lane & 7;         // B: 8 rows/inst

#define STAGE(bufi, kk)                                                        \
    {                                                                          \
        _Pragma("unroll")                                                      \
        for (int i = 0; i < 4; ++i) {                                          \
            int R  = wid * 16 + i * 4;                                         \
            int sw = (i & 1) * 4 + rlA;              /* (R+rlA)&7 */           \
            gld_lds16(&x[(size_t)(m0 + R + rlA) * 1024 + (kk) + ((cA ^ sw) * 4)],\
                      &As[bufi][R][0]);                                        \
        }                                                                      \
        _Pragma("unroll")                                                      \
        for (int i = 0; i < 4; ++i) {                                          \
            int R = wid * 32 + i * 8;                                          \
            gld_lds16(&Wb[(size_t)(n0 + R + rlB) * 1024 + (kk) + ((cB ^ rlB) * 8)],\
                      &Bs[bufi][R][0]);                                        \
        }                                                                      \
    }

    STAGE(0, 0);
    __syncthreads();

    const int sA = l16 & 7;
    for (int t = 0; t < 16; ++t) {
        const int buf = t & 1;
        if (t < 15) STAGE(buf ^ 1, (t + 1) * 64);     // DMA flies under MFMA
#pragma unroll
        for (int ks = 0; ks < 2; ++ks) {
            bf16x8 a[2], bb[4];
#pragma unroll
            for (int mt = 0; mt < 2; ++mt) {
                int r  = wm + mt * 16 + l16;
                int c0 = ks * 8 + quad * 2;
                f32x4 a0 = *(const f32x4*)&As[buf][r][(c0 ^ sA) * 4];
                f32x4 a1 = *(const f32x4*)&As[buf][r][((c0 + 1) ^ sA) * 4];
                a[mt] = (bf16x8){(__bf16)a0[0], (__bf16)a0[1], (__bf16)a0[2], (__bf16)a0[3],
                                 (__bf16)a1[0], (__bf16)a1[1], (__bf16)a1[2], (__bf16)a1[3]};
            }
#pragma unroll
            for (int nt = 0; nt < 4; ++nt) {
                int r  = wn + nt * 16 + l16;
                int cc = (ks * 4 + quad) ^ sA;
                bb[nt] = *(const bf16x8*)&Bs[buf][r][cc * 8];
            }
#pragma unroll
            for (int mt = 0; mt < 2; ++mt)
#pragma unroll
                for (int nt = 0; nt < 4; ++nt)
                    acc[mt][nt] = MFMA16(a[mt], bb[nt], acc[mt][nt]);
        }
        __syncthreads();   // drains tile t+1's DMA (vmcnt 0) + barrier
    }

    const float* bias = (which == 0) ? bq : (which == 1) ? bk : bv;
    if (which < 2) {
        __bf16* dst = (which == 0) ? Qb : Kb;
#pragma unroll
        for (int nt = 0; nt < 4; ++nt) {
            int col = wn + nt * 16 + l16;
            float bvv = bias[col];
#pragma unroll
            for (int mt = 0; mt < 2; ++mt)
#pragma unroll
                for (int r = 0; r < 4; ++r) {
                    int row = m0 + wm + mt * 16 + quad * 4 + r;
                    dst[(size_t)row * 128 + col] = (__bf16)(acc[mt][nt][r] + bvv);
                }
        }
    } else {
#pragma unroll
        for (int nt = 0; nt < 4; ++nt) {
            int col = wn + nt * 16 + l16;               // head index
            float bvv = bias[col];
#pragma unroll
            for (int mt = 0; mt < 2; ++mt) {
                int row = m0 + wm + mt * 16 + quad * 4;
                int bb_ = row >> 12, s = row & 4095;
                bf16x4 pk = {(__bf16)(acc[mt][nt][0] + bvv),
                             (__bf16)(acc[mt][nt][1] + bvv),
                             (__bf16)(acc[mt][nt][2] + bvv),
                             (__bf16)(acc[mt][nt][3] + bvv)};
                *(bf16x4*)&Vt[((size_t)(bb_ * 128 + col)) * 4096 + s] = pk;
            }
        }
    }
#undef STAGE
}

// -------------------------------------------------------------- flash_attn --
// v13: K staged in LDS via gld_lds, double-buffered, XOR-swizzled; one
// barrier per iter. V direct-from-global with prefetch. plT per-wave P^T.
// C=10 fixed -> 476 blocks. LDS 50KB -> 3 blocks/CU; VGPR target <=128.
__global__ __launch_bounds__(256, 2) void flash_attn(
    const __bf16* __restrict__ Qb, const __bf16* __restrict__ Kb,
    const __bf16* __restrict__ Vt, const int* __restrict__ mask,
    float* __restrict__ ml, __bf16* __restrict__ pex)
{
    __shared__ __align__(16) char smem[51200];
    __bf16 (*Ks)[64][128] = (__bf16(*)[64][128])smem;            // 32 KiB dbuf
    __bf16 (*plT)[32][72] = (__bf16(*)[32][72])(smem + 32768);   // 18 KiB
    __bf16 (*OL)[136]     = (__bf16(*)[136])smem;                // epilogue overlay

    // ---- block -> (T, b, j): n(T)=ceil((T+1)/5) chunks of <=10 key-iters ----
    int ii = blockIdx.x, T = 0, n, cum = 0;
    for (;; ++T) {
        n = (T + 5) / 5;
        if (ii < 4 * n) break;
        ii -= 4 * n;
        cum += n;
    }
    const int b  = ii / n;
    const int j  = ii % n;
    const int nk = 2 * (T + 1);
    const int t0 = j * 10;
    const int t1 = (nk < t0 + 10) ? nk : (t0 + 10);
    const int r0 = T * 128;
    const int slot = b * 119 + cum + j;      // ml/pex slot id (476 total)

    const int tid = threadIdx.x, wid = tid >> 6, lane = tid & 63;
    const int quad = lane >> 4, l16 = lane & 15;
    const int qw = r0 + wid * 32;                      // wave's q base
    const size_t sb = (size_t)b * 4096;
    const float qs = 0.08838834764831845f * 1.4426950408889634f; // scale*log2e

    const int rlK = lane >> 4, cK = lane & 15;         // K staging map
    const int sK  = l16 & 7;                           // K read swizzle

#define STAGE_K(bufi, kk)                                                      \
    {                                                                          \
        _Pragma("unroll")                                                      \
        for (int i_ = 0; i_ < 4; ++i_) {                                       \
            int R_   = wid * 16 + i_ * 4;                                      \
            int row_ = R_ + rlK;                                               \
            gld_lds16(&Kb[(sb + (kk) + row_) * 128 + ((cK ^ (row_ & 7)) * 8)], \
                      &Ks[bufi][R_][0]);                                       \
        }                                                                      \
    }

    bf16x8 qf[2][4];                                   // Q B-frags, scale folded
#pragma unroll
    for (int nf = 0; nf < 2; ++nf)
#pragma unroll
        for (int ks = 0; ks < 4; ++ks) {
            qf[nf][ks] = *(const bf16x8*)
                &Qb[(sb + qw + nf * 16 + l16) * 128 + ks * 32 + quad * 8];
#pragma unroll
            for (int e = 0; e < 8; ++e)
                qf[nf][ks][e] = (__bf16)((float)qf[nf][ks][e] * qs);
        }

    float mi[2] = {-1e30f, -1e30f}, li[2] = {0.f, 0.f};
    const f32x4 fzero = {0.f, 0.f, 0.f, 0.f};
    f32x4 o[8][2];                                     // O^T: 8 head-frags x 2 q-frags
#pragma unroll
    for (int hf = 0; hf < 8; ++hf)
#pragma unroll
        for (int nf = 0; nf < 2; ++nf) o[hf][nf] = fzero;

    const __bf16* vb = Vt + ((size_t)b * 128 + l16) * 4096 + quad * 8;

    STAGE_K(0, t0 * 64);
    __syncthreads();

    for (int t = t0; t < t1; ++t) {
        const int k0 = t * 64;
        const int buf = (t - t0) & 1;
        if (t + 1 < t1) STAGE_K(buf ^ 1, k0 + 64);     // DMA flies under compute
        const int mv = mask[sb + k0 + lane];

        // ---- S^T = K Q^T from LDS: rows=keys(64, 4 mf), cols=q(32, 2 nf) ----
        f32x4 s[4][2];
#pragma unroll
        for (int mf = 0; mf < 4; ++mf)
#pragma unroll
            for (int nf = 0; nf < 2; ++nf) s[mf][nf] = fzero;
        __builtin_amdgcn_s_setprio(1);
#pragma unroll
        for (int ks = 0; ks < 4; ++ks) {
            bf16x8 a[4];
#pragma unroll
            for (int mf = 0; mf < 4; ++mf)
                a[mf] = *(const bf16x8*)
                    &Ks[buf][mf * 16 + l16][((ks * 4 + quad) ^ sK) * 8];
#pragma unroll
            for (int mf = 0; mf < 4; ++mf)
#pragma unroll
                for (int nf = 0; nf < 2; ++nf)
                    s[mf][nf] = MFMA16(a[mf], qf[nf][ks], s[mf][nf]);
        }
        __builtin_amdgcn_s_setprio(0);
        // prefetch PV first half's V frags above the softmax (hides L2 latency)
        bf16x8 va0[8];
#pragma unroll
        for (int hf = 0; hf < 8; ++hf)
            va0[hf] = *(const bf16x8*)&vb[(size_t)(hf * 16) * 4096 + k0];

        // ---- masking (C-layout: key = mf*16+quad*4+r, q = qw+nf*16+l16) ----
        unsigned long long mb = __ballot(mv != 0);
        if (mb != ~0ull || k0 + 63 > qw) {
#pragma unroll
            for (int mf = 0; mf < 4; ++mf)
#pragma unroll
                for (int r = 0; r < 4; ++r) {
                    int kl = mf * 16 + quad * 4 + r;
                    bool mok = (mb >> kl) & 1;
                    int kc = k0 + kl;
#pragma unroll
                    for (int nf = 0; nf < 2; ++nf) {
                        int q = qw + nf * 16 + l16;
                        bool ok = mok && (kc <= q);
                        s[mf][nf][r] = ok ? s[mf][nf][r] : -1e30f;
                    }
                }
        }
        // ---- online softmax per q (log2 domain; reduce over quads) ----
#pragma unroll
        for (int nf = 0; nf < 2; ++nf) {
            float mx = s[0][nf][0];
#pragma unroll
            for (int mf = 0; mf < 4; ++mf)
#pragma unroll
                for (int r = 0; r < 4; ++r) mx = fmaxf(mx, s[mf][nf][r]);
            mx = fmaxf(mx, __shfl_xor(mx, 16));
            mx = fmaxf(mx, __shfl_xor(mx, 32));
            float mnew  = fmaxf(mi[nf], mx);
            float alpha = EXP2F(mi[nf] - mnew);
            float rs = 0.f;
#pragma unroll
            for (int mf = 0; mf < 4; ++mf)
#pragma unroll
                for (int r = 0; r < 4; ++r) {
                    float sv = s[mf][nf][r];
                    float p = (sv < -5e29f) ? 0.f : EXP2F(sv - mnew);
                    s[mf][nf][r] = p;
                    rs += p;
                }
            rs += __shfl_xor(rs, 16);
            rs += __shfl_xor(rs, 32);
            li[nf] = li[nf] * alpha + rs;
            mi[nf] = mnew;
#pragma unroll
            for (int hf = 0; hf < 8; ++hf) {
                o[hf][nf][0] *= alpha; o[hf][nf][1] *= alpha;
                o[hf][nf][2] *= alpha; o[hf][nf][3] *= alpha;
            }
            // pack P (consecutive keys in-lane) -> b32 LDS writes
            int ql = nf * 16 + l16;
#pragma unroll
            for (int mf = 0; mf < 4; ++mf) {
                bf16x2 w0 = {(__bf16)s[mf][nf][0], (__bf16)s[mf][nf][1]};
                bf16x2 w1 = {(__bf16)s[mf][nf][2], (__bf16)s[mf][nf][3]};
                *(bf16x2*)&plT[wid][ql][mf * 16 + quad * 4]     = w0;
                *(bf16x2*)&plT[wid][ql][mf * 16 + quad * 4 + 2] = w1;
            }
        }
        asm volatile("s_waitcnt lgkmcnt(0)" ::: "memory"); // per-wave DS order
        // ---- O^T += V^T P^T (V frags straight from global) ----
        bf16x8 pb0[2], pb1[2];
#pragma unroll
        for (int nf = 0; nf < 2; ++nf) {
            pb0[nf] = *(const bf16x8*)&plT[wid][nf * 16 + l16][quad * 8];
            pb1[nf] = *(const bf16x8*)&plT[wid][nf * 16 + l16][32 + quad * 8];
        }
        bf16x8 va1[8];
#pragma unroll
        for (int hf = 0; hf < 8; ++hf)
            va1[hf] = *(const bf16x8*)&vb[(size_t)(hf * 16) * 4096 + k0 + 32];
        __builtin_amdgcn_s_setprio(1);
#pragma unroll
        for (int hf = 0; hf < 8; ++hf)
#pragma unroll
            for (int nf = 0; nf < 2; ++nf)
                o[hf][nf] = MFMA16(va0[hf], pb0[nf], o[hf][nf]);
#pragma unroll
        for (int hf = 0; hf < 8; ++hf)
#pragma unroll
            for (int nf = 0; nf < 2; ++nf)
                o[hf][nf] = MFMA16(va1[hf], pb1[nf], o[hf][nf]);
        __builtin_amdgcn_s_setprio(0);
        __syncthreads();   // drains next-tile K DMA; guards Ks[buf] reuse
    }

    // ---- epilogue: transpose O^T via LDS (overlay), bf16 partial store ----
    float inv[2];
#pragma unroll
    for (int nf = 0; nf < 2; ++nf) inv[nf] = (li[nf] > 0.f) ? 1.0f / li[nf] : 0.f;
#pragma unroll
    for (int nf = 0; nf < 2; ++nf) {
        int ql = wid * 32 + nf * 16 + l16;
#pragma unroll
        for (int hf = 0; hf < 8; ++hf) {
            int hd = hf * 16 + quad * 4;
            bf16x2 w0 = {(__bf16)(o[hf][nf][0] * inv[nf]), (__bf16)(o[hf][nf][1] * inv[nf])};
            bf16x2 w1 = {(__bf16)(o[hf][nf][2] * inv[nf]), (__bf16)(o[hf][nf][3] * inv[nf])};
            *(bf16x2*)&OL[ql][hd]     = w0;
            *(bf16x2*)&OL[ql][hd + 2] = w1;
        }
        if (quad == 0) {
            size_t base = ((size_t)slot * 128 + ql) * 2;
            ml[base]     = mi[nf];
            ml[base + 1] = li[nf];
        }
    }
    __syncthreads();
    __bf16* dst = pex + (size_t)slot * 16384;
    {
        int qrow = tid >> 1, cb2 = (tid & 1) * 64;
#pragma unroll
        for (int i = 0; i < 8; ++i) {
            bf16x8 v = *(const bf16x8*)&OL[qrow][cb2 + i * 8];
            *(bf16x8*)&dst[(size_t)qrow * 128 + cb2 + i * 8] = v;
        }
    }
#undef STAGE_K
}

// ----------------------------------------------------------------- mergeN ---
// v13: grid (32,4,4) = 512 blocks (was 128 at ~0.5/CU). Each block: 32 q-rows
// x 128 heads of one (b,T) tile. All partials in pex -> pure streaming, no
// LDS, no barrier, no out-aliasing hazard.
__global__ __launch_bounds__(256) void mergeN(
    float* __restrict__ out, const float* __restrict__ ml,
    const __bf16* __restrict__ pex)
{
    const int T = blockIdx.x, b = blockIdx.y, z = blockIdx.z;
    int cum = 0;
    for (int tt = 0; tt < T; ++tt) cum += (tt + 5) / 5;
    const int n  = (T + 5) / 5;
    const int r0 = T * 128;
    const size_t sb = (size_t)b * 4096;
    const int ql = z * 32 + (threadIdx.x >> 3);
    const int ch = (threadIdx.x & 7) * 16;
    const int slot0 = b * 119 + cum;

    float mm = -1e30f;
    for (int jj = 0; jj < n; ++jj)
        mm = fmaxf(mm, ml[((size_t)(slot0 + jj) * 128 + ql) * 2]);

    float acc[16];
#pragma unroll
    for (int k = 0; k < 16; ++k) acc[k] = 0.f;
    float den = 0.f;
    for (int jj = 0; jj < n; ++jj) {
        size_t base = ((size_t)(slot0 + jj) * 128 + ql) * 2;
        float m = ml[base], l = ml[base + 1];
        float w = (l > 0.f) ? EXP2F(m - mm) * l : 0.f;
        den += w;
        const __bf16* p = pex + (size_t)(slot0 + jj) * 16384
                        + (size_t)ql * 128 + ch;
        bf16x8 v0 = *(const bf16x8*)&p[0];
        bf16x8 v1 = *(const bf16x8*)&p[8];
#pragma unroll
        for (int e = 0; e < 8; ++e) {
            acc[e]     += w * (float)v0[e];
            acc[8 + e] += w * (float)v1[e];
        }
    }
    float sc = (den > 0.f) ? 1.0f / den : 0.f;
    float* op = &out[(sb + r0 + ql) * 128 + ch];
#pragma unroll
    for (int q2 = 0; q2 < 4; ++q2) {
        float4 v = {acc[q2 * 4 + 0] * sc, acc[q2 * 4 + 1] * sc,
                    acc[q2 * 4 + 2] * sc, acc[q2 * 4 + 3] * sc};
        *(float4*)&op[q2 * 4] = v;
    }
}

// ----------------------------------------------------------------- launch ---
extern "C" void kernel_launch(void* const* d_in, const int* in_sizes, int n_in,
                              void* d_out, int out_size, void* d_ws, size_t ws_size,
                              hipStream_t stream)
{
    const float* x    = (const float*)d_in[0];
    const int*   mask = (const int*)d_in[1];
    const float* Wq   = (const float*)d_in[2];
    const float* bq   = (const float*)d_in[3];
    const float* Wk   = (const float*)d_in[4];
    const float* bk   = (const float*)d_in[5];
    const float* Wv   = (const float*)d_in[6];
    const float* bv   = (const float*)d_in[7];
    float* out = (float*)d_out;

    char* ws = (char*)d_ws;
    __bf16* Qb  = (__bf16*)ws;                        // 4 MiB
    __bf16* Kb  = Qb + (size_t)16384 * 128;           // 4 MiB
    __bf16* Vt  = Kb + (size_t)16384 * 128;           // 4 MiB ([b][h][s])
    __bf16* Wb  = Vt + (size_t)16384 * 128;           // 768 KiB @ 12,582,912
    float*  ml  = (float*)(ws + 12582912);            // 476 KiB, overlays dead Wb
    __bf16* pex = (__bf16*)(ws + 13369344);           // 14.9 MiB (476 x 32 KiB)

    prep_w<<<384, 256, 0, stream>>>(Wq, Wk, Wv, Wb);
    qkv_gemm<<<768, 256, 0, stream>>>(x, Wb, bq, bk, bv, Qb, Kb, Vt);
    flash_attn<<<476, 256, 0, stream>>>(Qb, Kb, Vt, mask, ml, pex);
    mergeN<<<dim3(32, 4, 4), 256, 0, stream>>>(out, ml, pex);
}